// Round 4
// baseline (16888.135 us; speedup 1.0000x reference)
//
#include <hip/hip_runtime.h>
#include <math.h>

#define TT 96
#define VV 32000
#define EPSF 1e-8f

typedef __attribute__((ext_vector_type(8))) short short8;
typedef __attribute__((ext_vector_type(4))) float f4v;

__device__ __forceinline__ float wsum64(float v){
  #pragma unroll
  for (int m=32;m>0;m>>=1) v += __shfl_xor(v,m);
  return v;
}
__device__ __forceinline__ float sigm(float x){ return 1.0f/(1.0f+expf(-x)); }
__device__ __forceinline__ float softplus(float x){ return x>20.0f ? x : log1pf(expf(x)); }
__device__ __forceinline__ float bf2f(unsigned short u){ return __uint_as_float(((unsigned)u)<<16); }
__device__ __forceinline__ unsigned short f2bf(float f){
  unsigned u = __float_as_uint(f);
  return (unsigned short)((u + 0x7fffu + ((u>>16)&1u)) >> 16);
}

// Core for pre-kernels: K-chunk of 512 over 16 lanes, xl stride 129 f4.
__device__ __forceinline__ void core_chunk(
  const float4* __restrict__ w0, const float4* __restrict__ w1,
  const float4* __restrict__ w2, const float4* __restrict__ w3,
  const float4* __restrict__ xl, int l, int g, float (&acc)[4][4])
{
  #pragma unroll
  for (int kt=0; kt<8; kt++){
    int i = kt*16 + l;
    float4 a0=w0[i], a1=w1[i], a2=w2[i], a3=w3[i];
    #pragma unroll
    for (int j=0;j<4;j++){
      float4 x = xl[(4*g+j)*129 + i];
      acc[0][j] += a0.x*x.x + a0.y*x.y + a0.z*x.z + a0.w*x.w;
      acc[1][j] += a1.x*x.x + a1.y*x.y + a1.z*x.z + a1.w*x.w;
      acc[2][j] += a2.x*x.x + a2.y*x.y + a2.z*x.z + a2.w*x.w;
      acc[3][j] += a3.x*x.x + a3.y*x.y + a3.z*x.z + a3.w*x.w;
    }
  }
}

__device__ __forceinline__ float reduce_pick(float (&acc)[4][4], int l){
  float r = 0.f;
  #pragma unroll
  for (int ri=0;ri<4;ri++)
  #pragma unroll
  for (int j=0;j<4;j++){
    float v = acc[ri][j];
    v += __shfl_xor(v,1); v += __shfl_xor(v,2);
    v += __shfl_xor(v,4); v += __shfl_xor(v,8);
    if (l == ri*4+j) r = v;
  }
  return r;
}

// ---------------- persistent sequential kernel ----------------

// 16-row x 16-col tile over K=1024, xl stride 257 f4 (256 f4 per col).
__device__ __forceinline__ float tile16(
  const float* __restrict__ W, int row0, int ldw,
  const float4* __restrict__ xl, int l, int g)
{
  const float4* w0 = (const float4*)(W + (size_t)(row0+0)*ldw);
  const float4* w1 = (const float4*)(W + (size_t)(row0+1)*ldw);
  const float4* w2 = (const float4*)(W + (size_t)(row0+2)*ldw);
  const float4* w3 = (const float4*)(W + (size_t)(row0+3)*ldw);
  float acc[4][4] = {};
  #pragma unroll
  for (int kt=0; kt<16; kt++){
    int i = kt*16 + l;
    float4 a0=w0[i], a1=w1[i], a2=w2[i], a3=w3[i];
    #pragma unroll
    for (int j=0;j<4;j++){
      float4 x = xl[(4*g+j)*257 + i];
      acc[0][j] += a0.x*x.x + a0.y*x.y + a0.z*x.z + a0.w*x.w;
      acc[1][j] += a1.x*x.x + a1.y*x.y + a1.z*x.z + a1.w*x.w;
      acc[2][j] += a2.x*x.x + a2.y*x.y + a2.z*x.z + a2.w*x.w;
      acc[3][j] += a3.x*x.x + a3.y*x.y + a3.z*x.z + a3.w*x.w;
    }
  }
  return reduce_pick(acc, l);
}

__device__ __forceinline__ void gbar(unsigned* bar, int rnd){
  __syncthreads();
  if (threadIdx.x == 0){
    __threadfence();
    __hip_atomic_fetch_add(bar, 1u, __ATOMIC_ACQ_REL, __HIP_MEMORY_SCOPE_AGENT);
    unsigned target = (unsigned)(rnd+1)*256u;
    while (__hip_atomic_load(bar, __ATOMIC_ACQUIRE, __HIP_MEMORY_SCOPE_AGENT) < target)
      __builtin_amdgcn_s_sleep(2);
  }
  __syncthreads();
}

__global__ __launch_bounds__(256) void k_seq(
  const float* __restrict__ Whh, const float* __restrict__ Wf1,
  const float* __restrict__ Pw, const float* __restrict__ Pa,
  const float* __restrict__ cf, const float* __restrict__ E,
  const float* __restrict__ C0, const int* __restrict__ ta,
  const int* __restrict__ nfp,
  float* __restrict__ hall, float* __restrict__ c, float* __restrict__ tf,
  float* __restrict__ Gw, int* __restrict__ aall,
  float* __restrict__ loss, unsigned* __restrict__ bar)
{
  __shared__ float4 xl[16*257];
  __shared__ float sS[64];
  __shared__ int sIdx;
  int tid = threadIdx.x, bx = blockIdx.x;
  int lane = tid & 63, wave = tid >> 6, l = lane & 15, g = lane >> 4;

  for (int i = 0; i <= 96; i++){
    // ---- Phase A: Gw = Whh@h_i (256 tiles) ; tf = relu(Wf1_h@h_i + cf) (64 tiles)
    {
      const float4* h4 = (const float4*)hall + (size_t)i*4096;
      for (int idx=tid; idx<4096; idx+=256){
        int b2 = idx>>8, ii = idx&255;
        xl[b2*257+ii] = h4[b2*256+ii];
      }
      __syncthreads();
      {
        float v = tile16(Whh, bx*16 + wave*4, 1024, xl, l, g);
        int row = bx*16 + wave*4 + (l>>2);
        int b = g*4 + (l&3);
        Gw[b*4096 + row] = v;
      }
      if (bx < 64){
        float v = tile16(Wf1, bx*16 + wave*4, 1536, xl, l, g);
        int rw = bx*16 + wave*4 + (l>>2);
        int b = g*4 + (l&3);
        tf[b*1024 + rw] = fmaxf(v + cf[b*1024 + rw], 0.f);
      }
    }
    gbar(bar, 2*i);

    // ---- Phase B: chain (attn for step i-1) + pointwise LSTM for step i
    if (bx < 16){
      int b = bx;
      float* tfl = (float*)xl;
      for (int j=tid; j<1024; j+=256) tfl[j] = tf[b*1024 + j];
      __syncthreads();
      int ai = 0;
      if (i >= 1){
        int f = tid>>2, q = tid&3;
        const float4* Er = (const float4*)(E + (size_t)(b*64+f)*1024) + q*64;
        const float4* tf4 = (const float4*)tfl + q*64;
        float s_ = 0.f;
        #pragma unroll 4
        for (int k2=0;k2<64;k2++){
          float4 e = Er[k2], x = tf4[k2];
          s_ += e.x*x.x + e.y*x.y + e.z*x.z + e.w*x.w;
        }
        s_ += __shfl_xor(s_,1); s_ += __shfl_xor(s_,2);
        if (q==0) sS[f] = s_ + C0[b*64+f];
        __syncthreads();
        if (tid < 64){
          int nf = nfp[b];
          float s = sS[tid];
          float mx = s;
          #pragma unroll
          for (int m=32;m>0;m>>=1) mx = fmaxf(mx, __shfl_xor(mx,m));
          float p = expf(s - mx);
          float ps = wsum64(p);
          p /= ps;
          bool mask = (tid < nf) || (tid == 63);
          float mval = mask ? (p + EPSF) : EPSF;
          float msum = wsum64(mval);
          float bv = mval; int bi2 = tid;
          #pragma unroll
          for (int m=32;m>0;m>>=1){
            float ov = __shfl_xor(bv,m); int oi = __shfl_xor(bi2,m);
            if (ov > bv || (ov == bv && oi < bi2)){ bv = ov; bi2 = oi; }
          }
          int at = ta[b*TT + (i-1)];
          float mat = __shfl(mval, at);
          if (tid == 0){
            atomicAdd(loss, -(logf(mat) - logf(msum)));
            sIdx = bi2;
          }
        }
        __syncthreads();
        ai = sIdx;
        if (tid == 0) aall[(i-1)*16 + b] = ai;
      }
      if (i <= 95){
        const float* gb = Gw + b*4096;
        const float* pw = Pw + (size_t)(b*96 + i)*4096;
        const float* pa = Pa + (size_t)(b*64 + ai)*4096;
        bool hasA = (i >= 1);
        for (int j=tid; j<1024; j+=256){
          float ig = gb[j]        + pw[j]        + (hasA ? pa[j]        : 0.f);
          float fg = gb[1024+j]   + pw[1024+j]   + (hasA ? pa[1024+j]   : 0.f);
          float gg = gb[2048+j]   + pw[2048+j]   + (hasA ? pa[2048+j]   : 0.f);
          float og = gb[3072+j]   + pw[3072+j]   + (hasA ? pa[3072+j]   : 0.f);
          float co = c[b*1024 + j];
          float cn = sigm(fg)*co + sigm(ig)*tanhf(gg);
          c[b*1024 + j] = cn;
          hall[((size_t)(i+1)*16 + b)*1024 + j] = sigm(og)*tanhf(cn);
        }
      }
    }
    gbar(bar, 2*i+1);
  }
}

// ---------------- phase 2: batched over all (b,t) ----------------

__global__ __launch_bounds__(256) void k2_cvp(
  const float* __restrict__ Wc1, const float* __restrict__ Wv1,
  const float* __restrict__ Wp1, const float* __restrict__ hall,
  const float* __restrict__ Ph, const int* __restrict__ aall,
  const float* __restrict__ bc1, const float* __restrict__ bv1,
  const float* __restrict__ bp1, float* __restrict__ tcvp)
{
  __shared__ float4 xl[16*129];
  int tid = threadIdx.x, lane = tid & 63, wave = tid >> 6;
  int l = lane & 15, g = lane >> 4;
  int seg = blockIdx.x >> 6;
  int rl0 = (blockIdx.x & 63)*16 + wave*4;
  const float* W = (seg==0)?Wc1:(seg==1)?Wv1:Wp1;
  const float4* h4 = (const float4*)hall + (size_t)(16 + blockIdx.y*16)*256;
  float acc[4][4] = {};
  for (int kc=0; kc<2; kc++){
    for (int idx=tid; idx<2048; idx+=256){
      int cc = idx>>7, i = idx&127;
      xl[cc*129+i] = h4[cc*256 + kc*128 + i];
    }
    __syncthreads();
    const float4* w0 = (const float4*)(W + (size_t)(rl0+0)*1536) + kc*128;
    const float4* w1 = (const float4*)(W + (size_t)(rl0+1)*1536) + kc*128;
    const float4* w2 = (const float4*)(W + (size_t)(rl0+2)*1536) + kc*128;
    const float4* w3 = (const float4*)(W + (size_t)(rl0+3)*1536) + kc*128;
    core_chunk(w0,w1,w2,w3, xl, l, g, acc);
    __syncthreads();
  }
  float v = reduce_pick(acc, l);
  int rl = rl0 + (l>>2);
  int n = blockIdx.y*16 + g*4 + (l&3);
  int b = n & 15;
  int ai = aall[n];
  const float* bias = (seg==0)?bc1:(seg==1)?bv1:bp1;
  float vv = v + Ph[((size_t)(b*64+ai))*3072 + seg*1024 + rl] + bias[rl];
  tcvp[(size_t)n*3072 + seg*1024 + rl] = fmaxf(vv, 0.f);
}

__global__ __launch_bounds__(256) void k2_heads2(
  const float* __restrict__ Wv2, const float* __restrict__ bv2,
  const float* __restrict__ Wp2, const float* __restrict__ bp2,
  const float* __restrict__ Wc2, const float* __restrict__ bc2,
  const float* __restrict__ tcvp, unsigned short* __restrict__ kvh,
  float* __restrict__ kpall, float* __restrict__ zlall)
{
  __shared__ float4 xl[16*129];
  int tid = threadIdx.x, lane = tid & 63, wave = tid >> 6;
  int l = lane & 15, g = lane >> 4;
  int bx = blockIdx.x;
  int seg = (bx < 32) ? 0 : (bx < 39) ? 1 : 2;
  int rb  = (seg==0) ? bx*16 : (seg==1) ? (bx-32)*16 : 0;
  int rl0 = rb + wave*4;
  const float* WS = (seg==0)?Wv2:(seg==1)?Wp2:Wc2;
  int maxr = (seg==0)?511:(seg==1)?99:0;
  int xoff4 = (seg==0)?256:(seg==1)?512:0;
  const float4* X4 = (const float4*)tcvp;
  float acc[4][4] = {};
  for (int kc=0; kc<2; kc++){
    for (int idx=tid; idx<2048; idx+=256){
      int cc = idx>>7, i = idx&127;
      xl[cc*129+i] = X4[(size_t)(blockIdx.y*16+cc)*768 + xoff4 + kc*128 + i];
    }
    __syncthreads();
    const float4* w0 = (const float4*)(WS + (size_t)min(rl0+0,maxr)*1024) + kc*128;
    const float4* w1 = (const float4*)(WS + (size_t)min(rl0+1,maxr)*1024) + kc*128;
    const float4* w2 = (const float4*)(WS + (size_t)min(rl0+2,maxr)*1024) + kc*128;
    const float4* w3 = (const float4*)(WS + (size_t)min(rl0+3,maxr)*1024) + kc*128;
    core_chunk(w0,w1,w2,w3, xl, l, g, acc);
    __syncthreads();
  }
  float v = reduce_pick(acc, l);
  int rl = rl0 + (l>>2);
  int n = blockIdx.y*16 + g*4 + (l&3);
  if (seg==0) kvh[(size_t)n*512 + rl] = f2bf(v + bv2[rl]);
  else if (seg==1){ if (rl < 100) kpall[n*128 + rl] = v + bp2[rl]; }
  else { if (rl == 0) zlall[n] = v + bc2[0]; }
}

__global__ __launch_bounds__(256) void k2_vocab(
  const unsigned short* __restrict__ embh, const unsigned short* __restrict__ kvh,
  float2* __restrict__ part)
{
  int wid = blockIdx.x*4 + (threadIdx.x>>6);
  int lane = threadIdx.x & 63;
  int mtile = wid % 500, ntile = wid / 500;
  int mrow = mtile*64 + (lane&15);
  int ncol = ntile*64 + (lane&15);
  int ko = (lane>>4)*8;
  f4v acc[4][4];
  #pragma unroll
  for (int i=0;i<4;i++)
  #pragma unroll
  for (int j=0;j<4;j++)
  #pragma unroll
  for (int r=0;r<4;r++) acc[i][j][r] = 0.f;
  for (int kk=0; kk<512; kk+=32){
    short8 af[4], bfr[4];
    #pragma unroll
    for (int i=0;i<4;i++)
      af[i] = *(const short8*)(embh + (size_t)(mrow+16*i)*512 + kk + ko);
    #pragma unroll
    for (int i=0;i<4;i++)
      bfr[i] = *(const short8*)(kvh + (size_t)(ncol+16*i)*512 + kk + ko);
    #pragma unroll
    for (int i=0;i<4;i++)
      #pragma unroll
      for (int j=0;j<4;j++)
        acc[i][j] = __builtin_amdgcn_mfma_f32_16x16x32_bf16(af[i], bfr[j], acc[i][j], 0,0,0);
  }
  int q = lane>>4;
  #pragma unroll
  for (int j=0;j<4;j++){
    float mx = -3.4e38f;
    #pragma unroll
    for (int i=0;i<4;i++)
    #pragma unroll
    for (int r=0;r<4;r++) mx = fmaxf(mx, acc[i][j][r]);
    mx = fmaxf(mx, __shfl_xor(mx,16));
    mx = fmaxf(mx, __shfl_xor(mx,32));
    float s = 0.f;
    #pragma unroll
    for (int i=0;i<4;i++)
    #pragma unroll
    for (int r=0;r<4;r++) s += expf(acc[i][j][r] - mx);
    s += __shfl_xor(s,16);
    s += __shfl_xor(s,32);
    if (q==0){
      int col = ntile*64 + 16*j + (lane&15);
      part[(size_t)col*500 + mtile] = make_float2(mx, s);
    }
  }
}

__global__ __launch_bounds__(256) void k2_vfin(
  const float2* __restrict__ part, const unsigned short* __restrict__ embh,
  const unsigned short* __restrict__ kvh, const int* __restrict__ tw,
  const int* __restrict__ tz, float* __restrict__ loss)
{
  __shared__ float red[4];
  int n = blockIdx.x, tid = threadIdx.x;
  int t = n>>4, b = n&15;
  float mx = -3.4e38f;
  for (int i=tid; i<500; i+=256) mx = fmaxf(mx, part[(size_t)n*500+i].x);
  #pragma unroll
  for (int m=32;m>0;m>>=1) mx = fmaxf(mx, __shfl_xor(mx,m));
  if ((tid&63)==0) red[tid>>6] = mx;
  __syncthreads();
  float M = fmaxf(fmaxf(red[0],red[1]), fmaxf(red[2],red[3]));
  __syncthreads();
  float s = 0.f;
  for (int i=tid; i<500; i+=256){
    float2 p = part[(size_t)n*500+i];
    s += p.y * expf(p.x - M);
  }
  s = wsum64(s);
  if ((tid&63)==0) red[tid>>6] = s;
  __syncthreads();
  float S = red[0]+red[1]+red[2]+red[3];
  __syncthreads();
  int w = tw[b*96+t];
  float d = 0.f;
  {
    const unsigned short* er = embh + (size_t)w*512;
    const unsigned short* kr = kvh + (size_t)n*512;
    for (int i=tid; i<512; i+=256) d += bf2f(er[i])*bf2f(kr[i]);
  }
  d = wsum64(d);
  if ((tid&63)==0) red[tid>>6] = d;
  __syncthreads();
  if (tid==0 && tz[b*96+t]==0){
    float D = red[0]+red[1]+red[2]+red[3];
    atomicAdd(loss, -(D - (M + logf(S))));
  }
}

__global__ __launch_bounds__(128) void k2_posz(
  const float* __restrict__ kpall, const float* __restrict__ zlall,
  const float* __restrict__ WP, const float* __restrict__ bP,
  const float* __restrict__ pmask, const int* __restrict__ tw,
  const int* __restrict__ ta, const int* __restrict__ tz,
  float* __restrict__ loss)
{
  __shared__ float pp[100];
  int n = blockIdx.x, tid = threadIdx.x;
  int t = n>>4, b = n&15;
  if (tid < 100){
    float s = bP[tid];
    const float* wr = WP + tid*100;
    const float* kp = kpall + n*128;
    for (int j=0;j<100;j++) s += wr[j]*kp[j];
    pp[tid] = s;
  }
  __syncthreads();
  if (tid == 0){
    float u = zlall[n];
    int z = tz[b*96+t], w = tw[b*96+t], at = ta[b*96+t];
    float tot = z ? softplus(-u) : softplus(u);
    if (z){
      float mxv = -1e30f;
      for (int l2=0;l2<100;l2++) mxv = fmaxf(mxv, pp[l2]);
      float se = 0.f;
      for (int l2=0;l2<100;l2++) se += expf(pp[l2]-mxv);
      const float* pm = pmask + ((size_t)b*64 + at)*100;
      float msum = 0.f, mw = 0.f;
      for (int l2=0;l2<100;l2++){
        float m = pm[l2]*(expf(pp[l2]-mxv)/se) + EPSF;
        msum += m;
        if (l2==w) mw = m;
      }
      tot += -(logf(mw) - logf(msum));
    }
    atomicAdd(loss, tot);
  }
}

// ---------------- phase 0: once-per-launch precompute ----------------

__global__ void k_cvt_emb(const float* __restrict__ emb, unsigned* __restrict__ out){
  const int n = VV*512/2;
  for (int idx = blockIdx.x*256 + threadIdx.x; idx < n; idx += gridDim.x*256){
    float2 v = ((const float2*)emb)[idx];
    unsigned a = __float_as_uint(v.x), b = __float_as_uint(v.y);
    unsigned ra = (a + 0x7fffu + ((a>>16)&1u)) >> 16;
    unsigned rb = (b + 0x7fffu + ((b>>16)&1u)) >> 16;
    out[idx] = ra | (rb<<16);
  }
}

__global__ void k_setup(const float* __restrict__ fe, const int* __restrict__ nfp,
                        float* __restrict__ e_k){
  int b = blockIdx.x, tid = threadIdx.x;
  int nf = nfp[b];
  for (int d=tid; d<512; d+=256){
    float s = 0.f;
    for (int f=0; f<nf; f++) s += fe[((size_t)b*64+f)*512 + d];
    e_k[b*512+d] = s/(float)nf;
  }
}

__global__ __launch_bounds__(256) void k_pre_pa(
  const float* __restrict__ Wih, const float* __restrict__ fe, float* __restrict__ Pa)
{
  __shared__ float4 xl[16*129];
  int tid = threadIdx.x, lane = tid & 63, wave = tid >> 6;
  int l = lane & 15, g = lane >> 4;
  int row0 = blockIdx.x*16 + wave*4;
  int c0 = blockIdx.y*16;
  const float4* fe4 = (const float4*)fe;
  for (int idx=tid; idx<2048; idx+=256){
    int cc = idx>>7, i = idx&127;
    xl[cc*129+i] = fe4[(size_t)(c0+cc)*128 + i];
  }
  __syncthreads();
  const float4* w0 = (const float4*)(Wih + (size_t)(row0+0)*1124);
  const float4* w1 = (const float4*)(Wih + (size_t)(row0+1)*1124);
  const float4* w2 = (const float4*)(Wih + (size_t)(row0+2)*1124);
  const float4* w3 = (const float4*)(Wih + (size_t)(row0+3)*1124);
  float acc[4][4] = {};
  core_chunk(w0,w1,w2,w3, xl, l, g, acc);
  float v = reduce_pick(acc, l);
  int row = row0 + (l>>2), c = c0 + g*4 + (l&3);
  Pa[(size_t)c*4096 + row] = v;
}

__global__ __launch_bounds__(256) void k_pre_ph(
  const float* __restrict__ Wc1, const float* __restrict__ Wv1,
  const float* __restrict__ Wp1, const float* __restrict__ fe, float* __restrict__ Ph)
{
  __shared__ float4 xl[16*129];
  int tid = threadIdx.x, lane = tid & 63, wave = tid >> 6;
  int l = lane & 15, g = lane >> 4;
  int row0 = blockIdx.x*16 + wave*4;
  int head = row0 >> 10, rl0 = row0 & 1023;
  const float* W = (head==0)?Wc1:(head==1)?Wv1:Wp1;
  int c0 = blockIdx.y*16;
  const float4* fe4 = (const float4*)fe;
  for (int idx=tid; idx<2048; idx+=256){
    int cc = idx>>7, i = idx&127;
    xl[cc*129+i] = fe4[(size_t)(c0+cc)*128 + i];
  }
  __syncthreads();
  const float4* w0 = (const float4*)(W + (size_t)(rl0+0)*1536 + 1024);
  const float4* w1 = (const float4*)(W + (size_t)(rl0+1)*1536 + 1024);
  const float4* w2 = (const float4*)(W + (size_t)(rl0+2)*1536 + 1024);
  const float4* w3 = (const float4*)(W + (size_t)(rl0+3)*1536 + 1024);
  float acc[4][4] = {};
  core_chunk(w0,w1,w2,w3, xl, l, g, acc);
  float v = reduce_pick(acc, l);
  int row = row0 + (l>>2), c = c0 + g*4 + (l&3);
  Ph[(size_t)c*3072 + row] = v;
}

__global__ __launch_bounds__(256) void k_pre_pw(
  const float* __restrict__ Wih, const float* __restrict__ emb,
  const int* __restrict__ tw, const int* __restrict__ tz,
  const float* __restrict__ bih, const float* __restrict__ bhh,
  float* __restrict__ Pw)
{
  __shared__ float4 xl[16*129];
  int tid = threadIdx.x, lane = tid & 63, wave = tid >> 6;
  int l = lane & 15, g = lane >> 4;
  int row0 = blockIdx.x*16 + wave*4;
  int c0 = blockIdx.y*16;
  for (int idx=tid; idx<2048; idx+=256){
    int cc = idx>>7, i = idx&127;
    int c = c0+cc, b = c/96, t2 = c - b*96;
    int w=0, z=0;
    if (t2>0){ w = tw[b*96+t2-1]; z = tz[b*96+t2-1]; }
    float4 v = make_float4(0.f,0.f,0.f,0.f);
    if (z==0) v = ((const float4*)emb)[(size_t)w*128 + i];
    xl[cc*129+i] = v;
  }
  __syncthreads();
  const float4* w0 = (const float4*)(Wih + (size_t)(row0+0)*1124 + 512);
  const float4* w1 = (const float4*)(Wih + (size_t)(row0+1)*1124 + 512);
  const float4* w2 = (const float4*)(Wih + (size_t)(row0+2)*1124 + 512);
  const float4* w3 = (const float4*)(Wih + (size_t)(row0+3)*1124 + 512);
  float acc[4][4] = {};
  core_chunk(w0,w1,w2,w3, xl, l, g, acc);
  float v = reduce_pick(acc, l);
  int row = row0 + (l>>2), c = c0 + g*4 + (l&3);
  int b = c/96, t2 = c - b*96;
  int w=0, z=0;
  if (t2>0){ w = tw[b*96+t2-1]; z = tz[b*96+t2-1]; }
  v += bih[row] + bhh[row];
  if (z) v += Wih[(size_t)row*1124 + 1024 + w];
  Pw[(size_t)c*4096 + row] = v;
}

__global__ __launch_bounds__(256) void k_pre_cf(
  const float* __restrict__ Wf1, const float* __restrict__ bf1,
  const float* __restrict__ e_k, float* __restrict__ cf)
{
  __shared__ float4 xl[16*129];
  int tid = threadIdx.x, lane = tid & 63, wave = tid >> 6;
  int l = lane & 15, g = lane >> 4;
  int row0 = blockIdx.x*16 + wave*4;
  const float4* ek4 = (const float4*)e_k;
  for (int idx=tid; idx<2048; idx+=256){
    int cc = idx>>7, i = idx&127;
    xl[cc*129+i] = ek4[cc*128 + i];
  }
  __syncthreads();
  const float4* w0 = (const float4*)(Wf1 + (size_t)(row0+0)*1536 + 1024);
  const float4* w1 = (const float4*)(Wf1 + (size_t)(row0+1)*1536 + 1024);
  const float4* w2 = (const float4*)(Wf1 + (size_t)(row0+2)*1536 + 1024);
  const float4* w3 = (const float4*)(Wf1 + (size_t)(row0+3)*1536 + 1024);
  float acc[4][4] = {};
  core_chunk(w0,w1,w2,w3, xl, l, g, acc);
  float v = reduce_pick(acc, l);
  int row = row0 + (l>>2), b = g*4 + (l&3);
  cf[b*1024 + row] = v + bf1[row];
}

// E[c][j] = sum_d fe[c][d] * Wf2[d][j]   (c = b*64+f)
__global__ __launch_bounds__(256) void k_pre_e(
  const float* __restrict__ fe, const float* __restrict__ Wf2, float* __restrict__ E)
{
  __shared__ float fel[16*512];
  int tid = threadIdx.x;
  int c0 = blockIdx.x*16;
  int j0 = blockIdx.y*256;
  const float4* fe4 = (const float4*)fe;
  for (int idx=tid; idx<2048; idx+=256)
    ((float4*)fel)[idx] = fe4[(size_t)c0*128 + idx];
  __syncthreads();
  int j = j0 + tid;
  float acc[16] = {};
  for (int d=0; d<512; d++){
    float wv = Wf2[d*1024 + j];
    #pragma unroll
    for (int cc=0; cc<16; cc++) acc[cc] += fel[cc*512+d]*wv;
  }
  #pragma unroll
  for (int cc=0; cc<16; cc++) E[(size_t)(c0+cc)*1024 + j] = acc[cc];
}

// C0[c] = fe[c] . bf2
__global__ void k_pre_c0(const float* __restrict__ fe, const float* __restrict__ bf2,
                         float* __restrict__ C0)
{
  int b = blockIdx.x, tid = threadIdx.x;
  int f = tid>>2, q = tid&3;
  const float4* fr = (const float4*)(fe + (size_t)(b*64+f)*512) + q*32;
  const float4* b4 = (const float4*)bf2 + q*32;
  float s = 0.f;
  for (int k=0;k<32;k++){ float4 a=fr[k], w=b4[k]; s += a.x*w.x+a.y*w.y+a.z*w.z+a.w*w.w; }
  s += __shfl_xor(s,1); s += __shfl_xor(s,2);
  if (q==0) C0[b*64+f] = s;
}

__global__ void k_out(const float* __restrict__ loss, float* __restrict__ out){
  out[0] = loss[0];
}

extern "C" void kernel_launch(void* const* d_in, const int* in_sizes, int n_in,
                              void* d_out, int out_size, void* d_ws, size_t ws_size,
                              hipStream_t stream)
{
  const float* fe   = (const float*)d_in[0];
  const float* pmask= (const float*)d_in[1];
  const float* emb  = (const float*)d_in[2];
  const float* Wih  = (const float*)d_in[3];
  const float* Whh  = (const float*)d_in[4];
  const float* bih  = (const float*)d_in[5];
  const float* bhh  = (const float*)d_in[6];
  const float* Wf1  = (const float*)d_in[7];
  const float* bf1  = (const float*)d_in[8];
  const float* Wf2  = (const float*)d_in[9];
  const float* bf2  = (const float*)d_in[10];
  const float* Wc1  = (const float*)d_in[11];
  const float* bc1  = (const float*)d_in[12];
  const float* Wc2  = (const float*)d_in[13];
  const float* bc2  = (const float*)d_in[14];
  const float* Wv1  = (const float*)d_in[15];
  const float* bv1  = (const float*)d_in[16];
  const float* Wv2  = (const float*)d_in[17];
  const float* bv2  = (const float*)d_in[18];
  const float* Wp1  = (const float*)d_in[19];
  const float* bp1  = (const float*)d_in[20];
  const float* Wp2  = (const float*)d_in[21];
  const float* bp2  = (const float*)d_in[22];
  const float* WP   = (const float*)d_in[23];
  const float* bP   = (const float*)d_in[24];
  const int* tw  = (const int*)d_in[25];
  const int* ta  = (const int*)d_in[26];
  const int* tz  = (const int*)d_in[27];
  const int* nfp = (const int*)d_in[28];

  float* w = (float*)d_ws;
  float*    loss  = w + 0;                        // [0..8): loss; [8..16): bar
  unsigned* bar   = (unsigned*)(w + 8);
  float*    c     = w + 16;                       // 16384
  float*    hall  = w + 16400;                    // 97*16384 (slot0 zeroed)
  int*      aall  = (int*)(w + 1605648);          // 1536
  float*    tf    = w + 1607184;                  // 16384
  float*    Gw    = w + 1623568;                  // 65536
  float*    e_k   = w + 1689104;                  // 8192
  float*    cf    = w + 1697296;                  // 16384
  float*    E     = w + 1713680;                  // 1048576
  float*    C0    = w + 2762256;                  // 1024
  float*    kpall = w + 2763280;                  // 196608
  float*    zlall = w + 2959888;                  // 1536
  float*    tcvp  = w + 2961424;                  // 4718592
  float2*   part  = (float2*)(w + 7680016);       // 1536000 floats
  unsigned short* kvh = (unsigned short*)(w + 9216016);  // 786432 ushorts (393216 f)
  float*    Pa    = w + 9609232;                  // 4194304
  float*    Ph    = w + 13803536;                 // 3145728
  float*    Pw    = w + 16949264;                 // 6291456
  unsigned* embbf = (unsigned*)(w + 23240720);    // 8192000 uints
  const unsigned short* embh = (const unsigned short*)embbf;

  // zero loss+bar, c, hall slot 0
  hipMemsetAsync(d_ws, 0, (size_t)(16 + 16384 + 16384)*4, stream);
  k_cvt_emb<<<8192,256,0,stream>>>(emb, embbf);
  k_setup<<<16,256,0,stream>>>(fe, nfp, e_k);
  k_pre_pa<<<dim3(256,64),256,0,stream>>>(Wih, fe, Pa);
  k_pre_ph<<<dim3(192,64),256,0,stream>>>(Wc1, Wv1, Wp1, fe, Ph);
  k_pre_pw<<<dim3(256,96),256,0,stream>>>(Wih, emb, tw, tz, bih, bhh, Pw);
  k_pre_cf<<<64,256,0,stream>>>(Wf1, bf1, e_k, cf);
  k_pre_e<<<dim3(64,4),256,0,stream>>>(fe, Wf2, E);
  k_pre_c0<<<16,256,0,stream>>>(fe, bf2, C0);

  k_seq<<<256,256,0,stream>>>(Whh, Wf1, Pw, Pa, cf, E, C0, ta, nfp,
                              hall, c, tf, Gw, aall, loss, bar);

  k2_cvp<<<dim3(192,96),256,0,stream>>>(Wc1, Wv1, Wp1, hall, Ph, aall,
                                        bc1, bv1, bp1, tcvp);
  k2_heads2<<<dim3(40,96),256,0,stream>>>(Wv2, bv2, Wp2, bp2, Wc2, bc2,
                                          tcvp, kvh, kpall, zlall);
  k2_vocab<<<3000,256,0,stream>>>(embh, kvh, part);
  k2_vfin<<<1536,256,0,stream>>>(part, embh, kvh, tw, tz, loss);
  k2_posz<<<1536,128,0,stream>>>(kpall, zlall, WP, bP, pmask, tw, ta, tz, loss);
  k_out<<<1,1,0,stream>>>(loss, (float*)d_out);
}

// Round 5
// 6847.840 us; speedup vs baseline: 2.4662x; 2.4662x over previous
//
#include <hip/hip_runtime.h>
#include <math.h>

#define TT 96
#define VV 32000
#define EPSF 1e-8f

typedef __attribute__((ext_vector_type(8))) short short8;
typedef __attribute__((ext_vector_type(4))) float f4v;

__device__ __forceinline__ float wsum64(float v){
  #pragma unroll
  for (int m=32;m>0;m>>=1) v += __shfl_xor(v,m);
  return v;
}
__device__ __forceinline__ float sigm(float x){ return 1.0f/(1.0f+expf(-x)); }
__device__ __forceinline__ float softplus(float x){ return x>20.0f ? x : log1pf(expf(x)); }
__device__ __forceinline__ float bf2f(unsigned short u){ return __uint_as_float(((unsigned)u)<<16); }
__device__ __forceinline__ unsigned short f2bf(float f){
  unsigned u = __float_as_uint(f);
  return (unsigned short)((u + 0x7fffu + ((u>>16)&1u)) >> 16);
}

// ---- L2-bypassing (agent-coherent) loads/stores for cross-block data ----
__device__ __forceinline__ float ld_cohf(const float* p){
  return __hip_atomic_load((float*)p, __ATOMIC_RELAXED, __HIP_MEMORY_SCOPE_AGENT);
}
__device__ __forceinline__ float2 ld_cohf2(const float* p){
  unsigned long long u = __hip_atomic_load((unsigned long long*)p,
                          __ATOMIC_RELAXED, __HIP_MEMORY_SCOPE_AGENT);
  float2 r; r.x = __uint_as_float((unsigned)u); r.y = __uint_as_float((unsigned)(u>>32));
  return r;
}
__device__ __forceinline__ void st_cohf(float* p, float v){
  __hip_atomic_store(p, v, __ATOMIC_RELAXED, __HIP_MEMORY_SCOPE_AGENT);
}

// Core for pre-kernels: K-chunk of 512 over 16 lanes, xl stride 129 f4.
__device__ __forceinline__ void core_chunk(
  const float4* __restrict__ w0, const float4* __restrict__ w1,
  const float4* __restrict__ w2, const float4* __restrict__ w3,
  const float4* __restrict__ xl, int l, int g, float (&acc)[4][4])
{
  #pragma unroll
  for (int kt=0; kt<8; kt++){
    int i = kt*16 + l;
    float4 a0=w0[i], a1=w1[i], a2=w2[i], a3=w3[i];
    #pragma unroll
    for (int j=0;j<4;j++){
      float4 x = xl[(4*g+j)*129 + i];
      acc[0][j] += a0.x*x.x + a0.y*x.y + a0.z*x.z + a0.w*x.w;
      acc[1][j] += a1.x*x.x + a1.y*x.y + a1.z*x.z + a1.w*x.w;
      acc[2][j] += a2.x*x.x + a2.y*x.y + a2.z*x.z + a2.w*x.w;
      acc[3][j] += a3.x*x.x + a3.y*x.y + a3.z*x.z + a3.w*x.w;
    }
  }
}

__device__ __forceinline__ float reduce_pick(float (&acc)[4][4], int l){
  float r = 0.f;
  #pragma unroll
  for (int ri=0;ri<4;ri++)
  #pragma unroll
  for (int j=0;j<4;j++){
    float v = acc[ri][j];
    v += __shfl_xor(v,1); v += __shfl_xor(v,2);
    v += __shfl_xor(v,4); v += __shfl_xor(v,8);
    if (l == ri*4+j) r = v;
  }
  return r;
}

// ---------------- persistent sequential kernel ----------------

// 16-row x 16-col tile over K=1024, xl stride 257 f4 (256 f4 per col).
__device__ __forceinline__ float tile16(
  const float* __restrict__ W, int row0, int ldw,
  const float4* __restrict__ xl, int l, int g)
{
  const float4* w0 = (const float4*)(W + (size_t)(row0+0)*ldw);
  const float4* w1 = (const float4*)(W + (size_t)(row0+1)*ldw);
  const float4* w2 = (const float4*)(W + (size_t)(row0+2)*ldw);
  const float4* w3 = (const float4*)(W + (size_t)(row0+3)*ldw);
  float acc[4][4] = {};
  #pragma unroll
  for (int kt=0; kt<16; kt++){
    int i = kt*16 + l;
    float4 a0=w0[i], a1=w1[i], a2=w2[i], a3=w3[i];
    #pragma unroll
    for (int j=0;j<4;j++){
      float4 x = xl[(4*g+j)*257 + i];
      acc[0][j] += a0.x*x.x + a0.y*x.y + a0.z*x.z + a0.w*x.w;
      acc[1][j] += a1.x*x.x + a1.y*x.y + a1.z*x.z + a1.w*x.w;
      acc[2][j] += a2.x*x.x + a2.y*x.y + a2.z*x.z + a2.w*x.w;
      acc[3][j] += a3.x*x.x + a3.y*x.y + a3.z*x.z + a3.w*x.w;
    }
  }
  return reduce_pick(acc, l);
}

// RELEASE increment (orders prior coherent stores), RELAXED spin (NO acquire →
// no L2 invalidate → read-only weights stay cached across the whole kernel).
__device__ __forceinline__ void gbar(unsigned* bar, int rnd){
  __syncthreads();
  if (threadIdx.x == 0){
    __hip_atomic_fetch_add(bar, 1u, __ATOMIC_RELEASE, __HIP_MEMORY_SCOPE_AGENT);
    unsigned target = (unsigned)(rnd+1)*256u;
    while (__hip_atomic_load(bar, __ATOMIC_RELAXED, __HIP_MEMORY_SCOPE_AGENT) < target)
      __builtin_amdgcn_s_sleep(2);
  }
  __syncthreads();
}

__global__ __launch_bounds__(256) void k_seq(
  const float* __restrict__ Whh, const float* __restrict__ Wf1,
  const float* __restrict__ Pw, const float* __restrict__ Pa,
  const float* __restrict__ cf, const float* __restrict__ E,
  const float* __restrict__ C0, const int* __restrict__ ta,
  const int* __restrict__ nfp,
  float* __restrict__ hall, float* __restrict__ c, float* __restrict__ tf,
  float* __restrict__ Gw, int* __restrict__ aall,
  float* __restrict__ loss, unsigned* __restrict__ bar)
{
  __shared__ float4 xl[16*257];
  __shared__ float sS[64];
  __shared__ int sIdx;
  int tid = threadIdx.x, bx = blockIdx.x;
  int lane = tid & 63, wave = tid >> 6, l = lane & 15, g = lane >> 4;

  for (int i = 0; i <= 96; i++){
    // ---- Phase A: Gw = Whh@h_i (256 tiles) ; tf = relu(Wf1_h@h_i + cf) (64 tiles)
    {
      const float* hsrc = hall + (size_t)i*16384;
      float2* xl2 = (float2*)xl;
      for (int idx=tid; idx<8192; idx+=256){
        int b2 = idx>>9, kk = idx&511;
        xl2[b2*514 + kk] = ld_cohf2(hsrc + b2*1024 + kk*2);
      }
      __syncthreads();
      {
        float v = tile16(Whh, bx*16 + wave*4, 1024, xl, l, g);
        int row = bx*16 + wave*4 + (l>>2);
        int b = g*4 + (l&3);
        st_cohf(&Gw[b*4096 + row], v);
      }
      if (bx < 64){
        float v = tile16(Wf1, bx*16 + wave*4, 1536, xl, l, g);
        int rw = bx*16 + wave*4 + (l>>2);
        int b = g*4 + (l&3);
        st_cohf(&tf[b*1024 + rw], fmaxf(v + cf[b*1024 + rw], 0.f));
      }
    }
    gbar(bar, 2*i);

    // ---- Phase B: chain (attn for step i-1) + pointwise LSTM for step i
    if (bx < 16){
      int b = bx;
      float* tfl = (float*)xl;
      for (int j=tid; j<512; j+=256)
        ((float2*)tfl)[j] = ld_cohf2(tf + b*1024 + j*2);
      __syncthreads();
      int ai = 0;
      if (i >= 1){
        int f = tid>>2, q = tid&3;
        const float4* Er = (const float4*)(E + (size_t)(b*64+f)*1024) + q*64;
        const float4* tf4 = (const float4*)tfl + q*64;
        float s_ = 0.f;
        #pragma unroll 4
        for (int k2=0;k2<64;k2++){
          float4 e = Er[k2], x = tf4[k2];
          s_ += e.x*x.x + e.y*x.y + e.z*x.z + e.w*x.w;
        }
        s_ += __shfl_xor(s_,1); s_ += __shfl_xor(s_,2);
        if (q==0) sS[f] = s_ + C0[b*64+f];
        __syncthreads();
        if (tid < 64){
          int nf = nfp[b];
          float s = sS[tid];
          float mx = s;
          #pragma unroll
          for (int m=32;m>0;m>>=1) mx = fmaxf(mx, __shfl_xor(mx,m));
          float p = expf(s - mx);
          float ps = wsum64(p);
          p /= ps;
          bool mask = (tid < nf) || (tid == 63);
          float mval = mask ? (p + EPSF) : EPSF;
          float msum = wsum64(mval);
          float bv = mval; int bi2 = tid;
          #pragma unroll
          for (int m=32;m>0;m>>=1){
            float ov = __shfl_xor(bv,m); int oi = __shfl_xor(bi2,m);
            if (ov > bv || (ov == bv && oi < bi2)){ bv = ov; bi2 = oi; }
          }
          int at = ta[b*TT + (i-1)];
          float mat = __shfl(mval, at);
          if (tid == 0){
            atomicAdd(loss, -(logf(mat) - logf(msum)));
            sIdx = bi2;
          }
        }
        __syncthreads();
        ai = sIdx;
        if (tid == 0) aall[(i-1)*16 + b] = ai;
      }
      if (i <= 95){
        const float* gb = Gw + b*4096;
        const float* pw = Pw + (size_t)(b*96 + i)*4096;
        const float* pa = Pa + (size_t)(b*64 + ai)*4096;
        bool hasA = (i >= 1);
        for (int j=tid; j<1024; j+=256){
          float ig = ld_cohf(gb+j)      + pw[j]      + (hasA ? pa[j]      : 0.f);
          float fg = ld_cohf(gb+1024+j) + pw[1024+j] + (hasA ? pa[1024+j] : 0.f);
          float gg = ld_cohf(gb+2048+j) + pw[2048+j] + (hasA ? pa[2048+j] : 0.f);
          float og = ld_cohf(gb+3072+j) + pw[3072+j] + (hasA ? pa[3072+j] : 0.f);
          float co = c[b*1024 + j];
          float cn = sigm(fg)*co + sigm(ig)*tanhf(gg);
          c[b*1024 + j] = cn;
          st_cohf(&hall[((size_t)(i+1)*16 + b)*1024 + j], sigm(og)*tanhf(cn));
        }
      }
    }
    gbar(bar, 2*i+1);
  }
}

// ---------------- phase 2: batched over all (b,t) ----------------

__global__ __launch_bounds__(256) void k2_cvp(
  const float* __restrict__ Wc1, const float* __restrict__ Wv1,
  const float* __restrict__ Wp1, const float* __restrict__ hall,
  const float* __restrict__ Ph, const int* __restrict__ aall,
  const float* __restrict__ bc1, const float* __restrict__ bv1,
  const float* __restrict__ bp1, float* __restrict__ tcvp)
{
  __shared__ float4 xl[16*129];
  int tid = threadIdx.x, lane = tid & 63, wave = tid >> 6;
  int l = lane & 15, g = lane >> 4;
  int seg = blockIdx.x >> 6;
  int rl0 = (blockIdx.x & 63)*16 + wave*4;
  const float* W = (seg==0)?Wc1:(seg==1)?Wv1:Wp1;
  const float4* h4 = (const float4*)hall + (size_t)(16 + blockIdx.y*16)*256;
  float acc[4][4] = {};
  for (int kc=0; kc<2; kc++){
    for (int idx=tid; idx<2048; idx+=256){
      int cc = idx>>7, i = idx&127;
      xl[cc*129+i] = h4[cc*256 + kc*128 + i];
    }
    __syncthreads();
    const float4* w0 = (const float4*)(W + (size_t)(rl0+0)*1536) + kc*128;
    const float4* w1 = (const float4*)(W + (size_t)(rl0+1)*1536) + kc*128;
    const float4* w2 = (const float4*)(W + (size_t)(rl0+2)*1536) + kc*128;
    const float4* w3 = (const float4*)(W + (size_t)(rl0+3)*1536) + kc*128;
    core_chunk(w0,w1,w2,w3, xl, l, g, acc);
    __syncthreads();
  }
  float v = reduce_pick(acc, l);
  int rl = rl0 + (l>>2);
  int n = blockIdx.y*16 + g*4 + (l&3);
  int b = n & 15;
  int ai = aall[n];
  const float* bias = (seg==0)?bc1:(seg==1)?bv1:bp1;
  float vv = v + Ph[((size_t)(b*64+ai))*3072 + seg*1024 + rl] + bias[rl];
  tcvp[(size_t)n*3072 + seg*1024 + rl] = fmaxf(vv, 0.f);
}

__global__ __launch_bounds__(256) void k2_heads2(
  const float* __restrict__ Wv2, const float* __restrict__ bv2,
  const float* __restrict__ Wp2, const float* __restrict__ bp2,
  const float* __restrict__ Wc2, const float* __restrict__ bc2,
  const float* __restrict__ tcvp, unsigned short* __restrict__ kvh,
  float* __restrict__ kpall, float* __restrict__ zlall)
{
  __shared__ float4 xl[16*129];
  int tid = threadIdx.x, lane = tid & 63, wave = tid >> 6;
  int l = lane & 15, g = lane >> 4;
  int bx = blockIdx.x;
  int seg = (bx < 32) ? 0 : (bx < 39) ? 1 : 2;
  int rb  = (seg==0) ? bx*16 : (seg==1) ? (bx-32)*16 : 0;
  int rl0 = rb + wave*4;
  const float* WS = (seg==0)?Wv2:(seg==1)?Wp2:Wc2;
  int maxr = (seg==0)?511:(seg==1)?99:0;
  int xoff4 = (seg==0)?256:(seg==1)?512:0;
  const float4* X4 = (const float4*)tcvp;
  float acc[4][4] = {};
  for (int kc=0; kc<2; kc++){
    for (int idx=tid; idx<2048; idx+=256){
      int cc = idx>>7, i = idx&127;
      xl[cc*129+i] = X4[(size_t)(blockIdx.y*16+cc)*768 + xoff4 + kc*128 + i];
    }
    __syncthreads();
    const float4* w0 = (const float4*)(WS + (size_t)min(rl0+0,maxr)*1024) + kc*128;
    const float4* w1 = (const float4*)(WS + (size_t)min(rl0+1,maxr)*1024) + kc*128;
    const float4* w2 = (const float4*)(WS + (size_t)min(rl0+2,maxr)*1024) + kc*128;
    const float4* w3 = (const float4*)(WS + (size_t)min(rl0+3,maxr)*1024) + kc*128;
    core_chunk(w0,w1,w2,w3, xl, l, g, acc);
    __syncthreads();
  }
  float v = reduce_pick(acc, l);
  int rl = rl0 + (l>>2);
  int n = blockIdx.y*16 + g*4 + (l&3);
  if (seg==0) kvh[(size_t)n*512 + rl] = f2bf(v + bv2[rl]);
  else if (seg==1){ if (rl < 100) kpall[n*128 + rl] = v + bp2[rl]; }
  else { if (rl == 0) zlall[n] = v + bc2[0]; }
}

__global__ __launch_bounds__(256) void k2_vocab(
  const unsigned short* __restrict__ embh, const unsigned short* __restrict__ kvh,
  float2* __restrict__ part)
{
  int wid = blockIdx.x*4 + (threadIdx.x>>6);
  int lane = threadIdx.x & 63;
  int mtile = wid % 500, ntile = wid / 500;
  int mrow = mtile*64 + (lane&15);
  int ncol = ntile*64 + (lane&15);
  int ko = (lane>>4)*8;
  f4v acc[4][4];
  #pragma unroll
  for (int i=0;i<4;i++)
  #pragma unroll
  for (int j=0;j<4;j++)
  #pragma unroll
  for (int r=0;r<4;r++) acc[i][j][r] = 0.f;
  for (int kk=0; kk<512; kk+=32){
    short8 af[4], bfr[4];
    #pragma unroll
    for (int i=0;i<4;i++)
      af[i] = *(const short8*)(embh + (size_t)(mrow+16*i)*512 + kk + ko);
    #pragma unroll
    for (int i=0;i<4;i++)
      bfr[i] = *(const short8*)(kvh + (size_t)(ncol+16*i)*512 + kk + ko);
    #pragma unroll
    for (int i=0;i<4;i++)
      #pragma unroll
      for (int j=0;j<4;j++)
        acc[i][j] = __builtin_amdgcn_mfma_f32_16x16x32_bf16(af[i], bfr[j], acc[i][j], 0,0,0);
  }
  int q = lane>>4;
  #pragma unroll
  for (int j=0;j<4;j++){
    float mx = -3.4e38f;
    #pragma unroll
    for (int i=0;i<4;i++)
    #pragma unroll
    for (int r=0;r<4;r++) mx = fmaxf(mx, acc[i][j][r]);
    mx = fmaxf(mx, __shfl_xor(mx,16));
    mx = fmaxf(mx, __shfl_xor(mx,32));
    float s = 0.f;
    #pragma unroll
    for (int i=0;i<4;i++)
    #pragma unroll
    for (int r=0;r<4;r++) s += expf(acc[i][j][r] - mx);
    s += __shfl_xor(s,16);
    s += __shfl_xor(s,32);
    if (q==0){
      int col = ntile*64 + 16*j + (lane&15);
      part[(size_t)col*500 + mtile] = make_float2(mx, s);
    }
  }
}

__global__ __launch_bounds__(256) void k2_vfin(
  const float2* __restrict__ part, const unsigned short* __restrict__ embh,
  const unsigned short* __restrict__ kvh, const int* __restrict__ tw,
  const int* __restrict__ tz, float* __restrict__ loss)
{
  __shared__ float red[4];
  int n = blockIdx.x, tid = threadIdx.x;
  int t = n>>4, b = n&15;
  float mx = -3.4e38f;
  for (int i=tid; i<500; i+=256) mx = fmaxf(mx, part[(size_t)n*500+i].x);
  #pragma unroll
  for (int m=32;m>0;m>>=1) mx = fmaxf(mx, __shfl_xor(mx,m));
  if ((tid&63)==0) red[tid>>6] = mx;
  __syncthreads();
  float M = fmaxf(fmaxf(red[0],red[1]), fmaxf(red[2],red[3]));
  __syncthreads();
  float s = 0.f;
  for (int i=tid; i<500; i+=256){
    float2 p = part[(size_t)n*500+i];
    s += p.y * expf(p.x - M);
  }
  s = wsum64(s);
  if ((tid&63)==0) red[tid>>6] = s;
  __syncthreads();
  float S = red[0]+red[1]+red[2]+red[3];
  __syncthreads();
  int w = tw[b*96+t];
  float d = 0.f;
  {
    const unsigned short* er = embh + (size_t)w*512;
    const unsigned short* kr = kvh + (size_t)n*512;
    for (int i=tid; i<512; i+=256) d += bf2f(er[i])*bf2f(kr[i]);
  }
  d = wsum64(d);
  if ((tid&63)==0) red[tid>>6] = d;
  __syncthreads();
  if (tid==0 && tz[b*96+t]==0){
    float D = red[0]+red[1]+red[2]+red[3];
    atomicAdd(loss, -(D - (M + logf(S))));
  }
}

__global__ __launch_bounds__(128) void k2_posz(
  const float* __restrict__ kpall, const float* __restrict__ zlall,
  const float* __restrict__ WP, const float* __restrict__ bP,
  const float* __restrict__ pmask, const int* __restrict__ tw,
  const int* __restrict__ ta, const int* __restrict__ tz,
  float* __restrict__ loss)
{
  __shared__ float pp[100];
  int n = blockIdx.x, tid = threadIdx.x;
  int t = n>>4, b = n&15;
  if (tid < 100){
    float s = bP[tid];
    const float* wr = WP + tid*100;
    const float* kp = kpall + n*128;
    for (int j=0;j<100;j++) s += wr[j]*kp[j];
    pp[tid] = s;
  }
  __syncthreads();
  if (tid == 0){
    float u = zlall[n];
    int z = tz[b*96+t], w = tw[b*96+t], at = ta[b*96+t];
    float tot = z ? softplus(-u) : softplus(u);
    if (z){
      float mxv = -1e30f;
      for (int l2=0;l2<100;l2++) mxv = fmaxf(mxv, pp[l2]);
      float se = 0.f;
      for (int l2=0;l2<100;l2++) se += expf(pp[l2]-mxv);
      const float* pm = pmask + ((size_t)b*64 + at)*100;
      float msum = 0.f, mw = 0.f;
      for (int l2=0;l2<100;l2++){
        float m = pm[l2]*(expf(pp[l2]-mxv)/se) + EPSF;
        msum += m;
        if (l2==w) mw = m;
      }
      tot += -(logf(mw) - logf(msum));
    }
    atomicAdd(loss, tot);
  }
}

// ---------------- phase 0: once-per-launch precompute ----------------

__global__ void k_cvt_emb(const float* __restrict__ emb, unsigned* __restrict__ out){
  const int n = VV*512/2;
  for (int idx = blockIdx.x*256 + threadIdx.x; idx < n; idx += gridDim.x*256){
    float2 v = ((const float2*)emb)[idx];
    unsigned a = __float_as_uint(v.x), b = __float_as_uint(v.y);
    unsigned ra = (a + 0x7fffu + ((a>>16)&1u)) >> 16;
    unsigned rb = (b + 0x7fffu + ((b>>16)&1u)) >> 16;
    out[idx] = ra | (rb<<16);
  }
}

__global__ void k_setup(const float* __restrict__ fe, const int* __restrict__ nfp,
                        float* __restrict__ e_k){
  int b = blockIdx.x, tid = threadIdx.x;
  int nf = nfp[b];
  for (int d=tid; d<512; d+=256){
    float s = 0.f;
    for (int f=0; f<nf; f++) s += fe[((size_t)b*64+f)*512 + d];
    e_k[b*512+d] = s/(float)nf;
  }
}

__global__ __launch_bounds__(256) void k_pre_pa(
  const float* __restrict__ Wih, const float* __restrict__ fe, float* __restrict__ Pa)
{
  __shared__ float4 xl[16*129];
  int tid = threadIdx.x, lane = tid & 63, wave = tid >> 6;
  int l = lane & 15, g = lane >> 4;
  int row0 = blockIdx.x*16 + wave*4;
  int c0 = blockIdx.y*16;
  const float4* fe4 = (const float4*)fe;
  for (int idx=tid; idx<2048; idx+=256){
    int cc = idx>>7, i = idx&127;
    xl[cc*129+i] = fe4[(size_t)(c0+cc)*128 + i];
  }
  __syncthreads();
  const float4* w0 = (const float4*)(Wih + (size_t)(row0+0)*1124);
  const float4* w1 = (const float4*)(Wih + (size_t)(row0+1)*1124);
  const float4* w2 = (const float4*)(Wih + (size_t)(row0+2)*1124);
  const float4* w3 = (const float4*)(Wih + (size_t)(row0+3)*1124);
  float acc[4][4] = {};
  core_chunk(w0,w1,w2,w3, xl, l, g, acc);
  float v = reduce_pick(acc, l);
  int row = row0 + (l>>2), c = c0 + g*4 + (l&3);
  Pa[(size_t)c*4096 + row] = v;
}

__global__ __launch_bounds__(256) void k_pre_ph(
  const float* __restrict__ Wc1, const float* __restrict__ Wv1,
  const float* __restrict__ Wp1, const float* __restrict__ fe, float* __restrict__ Ph)
{
  __shared__ float4 xl[16*129];
  int tid = threadIdx.x, lane = tid & 63, wave = tid >> 6;
  int l = lane & 15, g = lane >> 4;
  int row0 = blockIdx.x*16 + wave*4;
  int head = row0 >> 10, rl0 = row0 & 1023;
  const float* W = (head==0)?Wc1:(head==1)?Wv1:Wp1;
  int c0 = blockIdx.y*16;
  const float4* fe4 = (const float4*)fe;
  for (int idx=tid; idx<2048; idx+=256){
    int cc = idx>>7, i = idx&127;
    xl[cc*129+i] = fe4[(size_t)(c0+cc)*128 + i];
  }
  __syncthreads();
  const float4* w0 = (const float4*)(W + (size_t)(rl0+0)*1536 + 1024);
  const float4* w1 = (const float4*)(W + (size_t)(rl0+1)*1536 + 1024);
  const float4* w2 = (const float4*)(W + (size_t)(rl0+2)*1536 + 1024);
  const float4* w3 = (const float4*)(W + (size_t)(rl0+3)*1536 + 1024);
  float acc[4][4] = {};
  core_chunk(w0,w1,w2,w3, xl, l, g, acc);
  float v = reduce_pick(acc, l);
  int row = row0 + (l>>2), c = c0 + g*4 + (l&3);
  Ph[(size_t)c*3072 + row] = v;
}

__global__ __launch_bounds__(256) void k_pre_pw(
  const float* __restrict__ Wih, const float* __restrict__ emb,
  const int* __restrict__ tw, const int* __restrict__ tz,
  const float* __restrict__ bih, const float* __restrict__ bhh,
  float* __restrict__ Pw)
{
  __shared__ float4 xl[16*129];
  int tid = threadIdx.x, lane = tid & 63, wave = tid >> 6;
  int l = lane & 15, g = lane >> 4;
  int row0 = blockIdx.x*16 + wave*4;
  int c0 = blockIdx.y*16;
  for (int idx=tid; idx<2048; idx+=256){
    int cc = idx>>7, i = idx&127;
    int c = c0+cc, b = c/96, t2 = c - b*96;
    int w=0, z=0;
    if (t2>0){ w = tw[b*96+t2-1]; z = tz[b*96+t2-1]; }
    float4 v = make_float4(0.f,0.f,0.f,0.f);
    if (z==0) v = ((const float4*)emb)[(size_t)w*128 + i];
    xl[cc*129+i] = v;
  }
  __syncthreads();
  const float4* w0 = (const float4*)(Wih + (size_t)(row0+0)*1124 + 512);
  const float4* w1 = (const float4*)(Wih + (size_t)(row0+1)*1124 + 512);
  const float4* w2 = (const float4*)(Wih + (size_t)(row0+2)*1124 + 512);
  const float4* w3 = (const float4*)(Wih + (size_t)(row0+3)*1124 + 512);
  float acc[4][4] = {};
  core_chunk(w0,w1,w2,w3, xl, l, g, acc);
  float v = reduce_pick(acc, l);
  int row = row0 + (l>>2), c = c0 + g*4 + (l&3);
  int b = c/96, t2 = c - b*96;
  int w=0, z=0;
  if (t2>0){ w = tw[b*96+t2-1]; z = tz[b*96+t2-1]; }
  v += bih[row] + bhh[row];
  if (z) v += Wih[(size_t)row*1124 + 1024 + w];
  Pw[(size_t)c*4096 + row] = v;
}

__global__ __launch_bounds__(256) void k_pre_cf(
  const float* __restrict__ Wf1, const float* __restrict__ bf1,
  const float* __restrict__ e_k, float* __restrict__ cf)
{
  __shared__ float4 xl[16*129];
  int tid = threadIdx.x, lane = tid & 63, wave = tid >> 6;
  int l = lane & 15, g = lane >> 4;
  int row0 = blockIdx.x*16 + wave*4;
  const float4* ek4 = (const float4*)e_k;
  for (int idx=tid; idx<2048; idx+=256){
    int cc = idx>>7, i = idx&127;
    xl[cc*129+i] = ek4[cc*128 + i];
  }
  __syncthreads();
  const float4* w0 = (const float4*)(Wf1 + (size_t)(row0+0)*1536 + 1024);
  const float4* w1 = (const float4*)(Wf1 + (size_t)(row0+1)*1536 + 1024);
  const float4* w2 = (const float4*)(Wf1 + (size_t)(row0+2)*1536 + 1024);
  const float4* w3 = (const float4*)(Wf1 + (size_t)(row0+3)*1536 + 1024);
  float acc[4][4] = {};
  core_chunk(w0,w1,w2,w3, xl, l, g, acc);
  float v = reduce_pick(acc, l);
  int row = row0 + (l>>2), b = g*4 + (l&3);
  cf[b*1024 + row] = v + bf1[row];
}

// E[c][j] = sum_d fe[c][d] * Wf2[d][j]   (c = b*64+f)
__global__ __launch_bounds__(256) void k_pre_e(
  const float* __restrict__ fe, const float* __restrict__ Wf2, float* __restrict__ E)
{
  __shared__ float fel[16*512];
  int tid = threadIdx.x;
  int c0 = blockIdx.x*16;
  int j0 = blockIdx.y*256;
  const float4* fe4 = (const float4*)fe;
  for (int idx=tid; idx<2048; idx+=256)
    ((float4*)fel)[idx] = fe4[(size_t)c0*128 + idx];
  __syncthreads();
  int j = j0 + tid;
  float acc[16] = {};
  for (int d=0; d<512; d++){
    float wv = Wf2[d*1024 + j];
    #pragma unroll
    for (int cc=0; cc<16; cc++) acc[cc] += fel[cc*512+d]*wv;
  }
  #pragma unroll
  for (int cc=0; cc<16; cc++) E[(size_t)(c0+cc)*1024 + j] = acc[cc];
}

// C0[c] = fe[c] . bf2
__global__ void k_pre_c0(const float* __restrict__ fe, const float* __restrict__ bf2,
                         float* __restrict__ C0)
{
  int b = blockIdx.x, tid = threadIdx.x;
  int f = tid>>2, q = tid&3;
  const float4* fr = (const float4*)(fe + (size_t)(b*64+f)*512) + q*32;
  const float4* b4 = (const float4*)bf2 + q*32;
  float s = 0.f;
  for (int k=0;k<32;k++){ float4 a=fr[k], w=b4[k]; s += a.x*w.x+a.y*w.y+a.z*w.z+a.w*w.w; }
  s += __shfl_xor(s,1); s += __shfl_xor(s,2);
  if (q==0) C0[b*64+f] = s;
}

__global__ void k_out(const float* __restrict__ loss, float* __restrict__ out){
  out[0] = loss[0];
}

extern "C" void kernel_launch(void* const* d_in, const int* in_sizes, int n_in,
                              void* d_out, int out_size, void* d_ws, size_t ws_size,
                              hipStream_t stream)
{
  const float* fe   = (const float*)d_in[0];
  const float* pmask= (const float*)d_in[1];
  const float* emb  = (const float*)d_in[2];
  const float* Wih  = (const float*)d_in[3];
  const float* Whh  = (const float*)d_in[4];
  const float* bih  = (const float*)d_in[5];
  const float* bhh  = (const float*)d_in[6];
  const float* Wf1  = (const float*)d_in[7];
  const float* bf1  = (const float*)d_in[8];
  const float* Wf2  = (const float*)d_in[9];
  const float* bf2  = (const float*)d_in[10];
  const float* Wc1  = (const float*)d_in[11];
  const float* bc1  = (const float*)d_in[12];
  const float* Wc2  = (const float*)d_in[13];
  const float* bc2  = (const float*)d_in[14];
  const float* Wv1  = (const float*)d_in[15];
  const float* bv1  = (const float*)d_in[16];
  const float* Wv2  = (const float*)d_in[17];
  const float* bv2  = (const float*)d_in[18];
  const float* Wp1  = (const float*)d_in[19];
  const float* bp1  = (const float*)d_in[20];
  const float* Wp2  = (const float*)d_in[21];
  const float* bp2  = (const float*)d_in[22];
  const float* WP   = (const float*)d_in[23];
  const float* bP   = (const float*)d_in[24];
  const int* tw  = (const int*)d_in[25];
  const int* ta  = (const int*)d_in[26];
  const int* tz  = (const int*)d_in[27];
  const int* nfp = (const int*)d_in[28];

  float* w = (float*)d_ws;
  float*    loss  = w + 0;                        // [0..8): loss; [8..16): bar
  unsigned* bar   = (unsigned*)(w + 8);
  float*    c     = w + 16;                       // 16384
  float*    hall  = w + 16400;                    // 97*16384 (slot0 zeroed)
  int*      aall  = (int*)(w + 1605648);          // 1536
  float*    tf    = w + 1607184;                  // 16384
  float*    Gw    = w + 1623568;                  // 65536
  float*    e_k   = w + 1689104;                  // 8192
  float*    cf    = w + 1697296;                  // 16384
  float*    E     = w + 1713680;                  // 1048576
  float*    C0    = w + 2762256;                  // 1024
  float*    kpall = w + 2763280;                  // 196608
  float*    zlall = w + 2959888;                  // 1536
  float*    tcvp  = w + 2961424;                  // 4718592
  float2*   part  = (float2*)(w + 7680016);       // 1536000 floats
  unsigned short* kvh = (unsigned short*)(w + 9216016);  // 786432 ushorts (393216 f)
  float*    Pa    = w + 9609232;                  // 4194304
  float*    Ph    = w + 13803536;                 // 3145728
  float*    Pw    = w + 16949264;                 // 6291456
  unsigned* embbf = (unsigned*)(w + 23240720);    // 8192000 uints
  const unsigned short* embh = (const unsigned short*)embbf;

  // zero loss+bar, c, hall slot 0
  hipMemsetAsync(d_ws, 0, (size_t)(16 + 16384 + 16384)*4, stream);
  k_cvt_emb<<<8192,256,0,stream>>>(emb, embbf);
  k_setup<<<16,256,0,stream>>>(fe, nfp, e_k);
  k_pre_pa<<<dim3(256,64),256,0,stream>>>(Wih, fe, Pa);
  k_pre_ph<<<dim3(192,64),256,0,stream>>>(Wc1, Wv1, Wp1, fe, Ph);
  k_pre_pw<<<dim3(256,96),256,0,stream>>>(Wih, emb, tw, tz, bih, bhh, Pw);
  k_pre_cf<<<64,256,0,stream>>>(Wf1, bf1, e_k, cf);
  k_pre_e<<<dim3(64,4),256,0,stream>>>(fe, Wf2, E);
  k_pre_c0<<<16,256,0,stream>>>(fe, bf2, C0);

  k_seq<<<256,256,0,stream>>>(Whh, Wf1, Pw, Pa, cf, E, C0, ta, nfp,
                              hall, c, tf, Gw, aall, loss, bar);

  k2_cvp<<<dim3(192,96),256,0,stream>>>(Wc1, Wv1, Wp1, hall, Ph, aall,
                                        bc1, bv1, bp1, tcvp);
  k2_heads2<<<dim3(40,96),256,0,stream>>>(Wv2, bv2, Wp2, bp2, Wc2, bc2,
                                          tcvp, kvh, kpall, zlall);
  k2_vocab<<<3000,256,0,stream>>>(embh, kvh, part);
  k2_vfin<<<1536,256,0,stream>>>(part, embh, kvh, tw, tz, loss);
  k2_posz<<<1536,128,0,stream>>>(kpall, zlall, WP, bP, pmask, tw, ta, tz, loss);
  k_out<<<1,1,0,stream>>>(loss, (float*)d_out);
}

// Round 6
// 5486.002 us; speedup vs baseline: 3.0784x; 1.2482x over previous
//
#include <hip/hip_runtime.h>
#include <math.h>

#define TT 96
#define VV 32000
#define EPSF 1e-8f

typedef __attribute__((ext_vector_type(8))) short short8;
typedef __attribute__((ext_vector_type(4))) float f4v;

__device__ __forceinline__ float wsum64(float v){
  #pragma unroll
  for (int m=32;m>0;m>>=1) v += __shfl_xor(v,m);
  return v;
}
__device__ __forceinline__ float sigm(float x){ return 1.0f/(1.0f+expf(-x)); }
__device__ __forceinline__ float softplus(float x){ return x>20.0f ? x : log1pf(expf(x)); }
__device__ __forceinline__ float bf2f(unsigned short u){ return __uint_as_float(((unsigned)u)<<16); }
__device__ __forceinline__ unsigned short f2bf(float f){
  unsigned u = __float_as_uint(f);
  return (unsigned short)((u + 0x7fffu + ((u>>16)&1u)) >> 16);
}

// ---- cache-bypassing (agent-coherent) loads/stores for cross-block data ----
__device__ __forceinline__ float ld_cohf(const float* p){
  return __hip_atomic_load((float*)p, __ATOMIC_RELAXED, __HIP_MEMORY_SCOPE_AGENT);
}
__device__ __forceinline__ float2 ld_cohf2(const float* p){
  unsigned long long u = __hip_atomic_load((unsigned long long*)p,
                          __ATOMIC_RELAXED, __HIP_MEMORY_SCOPE_AGENT);
  float2 r; r.x = __uint_as_float((unsigned)u); r.y = __uint_as_float((unsigned)(u>>32));
  return r;
}
__device__ __forceinline__ void st_cohf(float* p, float v){
  __hip_atomic_store(p, v, __ATOMIC_RELAXED, __HIP_MEMORY_SCOPE_AGENT);
}
__device__ __forceinline__ int ld_flag(const int* p){
  return __hip_atomic_load((int*)p, __ATOMIC_RELAXED, __HIP_MEMORY_SCOPE_AGENT);
}
__device__ __forceinline__ void st_flag(int* p, int v){
  __hip_atomic_store(p, v, __ATOMIC_RELAXED, __HIP_MEMORY_SCOPE_AGENT);
}

// Core for pre-kernels: K-chunk of 512 over 16 lanes, xl stride 129 f4.
__device__ __forceinline__ void core_chunk(
  const float4* __restrict__ w0, const float4* __restrict__ w1,
  const float4* __restrict__ w2, const float4* __restrict__ w3,
  const float4* __restrict__ xl, int l, int g, float (&acc)[4][4])
{
  #pragma unroll
  for (int kt=0; kt<8; kt++){
    int i = kt*16 + l;
    float4 a0=w0[i], a1=w1[i], a2=w2[i], a3=w3[i];
    #pragma unroll
    for (int j=0;j<4;j++){
      float4 x = xl[(4*g+j)*129 + i];
      acc[0][j] += a0.x*x.x + a0.y*x.y + a0.z*x.z + a0.w*x.w;
      acc[1][j] += a1.x*x.x + a1.y*x.y + a1.z*x.z + a1.w*x.w;
      acc[2][j] += a2.x*x.x + a2.y*x.y + a2.z*x.z + a2.w*x.w;
      acc[3][j] += a3.x*x.x + a3.y*x.y + a3.z*x.z + a3.w*x.w;
    }
  }
}

__device__ __forceinline__ float reduce_pick(float (&acc)[4][4], int l){
  float r = 0.f;
  #pragma unroll
  for (int ri=0;ri<4;ri++)
  #pragma unroll
  for (int j=0;j<4;j++){
    float v = acc[ri][j];
    v += __shfl_xor(v,1); v += __shfl_xor(v,2);
    v += __shfl_xor(v,4); v += __shfl_xor(v,8);
    if (l == ri*4+j) r = v;
  }
  return r;
}

// ---------------- persistent sequential kernel ----------------

// 16-row x 16-col tile over K=1024, xl stride 257 f4 (256 f4 per col).
__device__ __forceinline__ float tile16(
  const float* __restrict__ W, int row0, int ldw,
  const float4* __restrict__ xl, int l, int g)
{
  const float4* w0 = (const float4*)(W + (size_t)(row0+0)*ldw);
  const float4* w1 = (const float4*)(W + (size_t)(row0+1)*ldw);
  const float4* w2 = (const float4*)(W + (size_t)(row0+2)*ldw);
  const float4* w3 = (const float4*)(W + (size_t)(row0+3)*ldw);
  float acc[4][4] = {};
  #pragma unroll
  for (int kt=0; kt<16; kt++){
    int i = kt*16 + l;
    float4 a0=w0[i], a1=w1[i], a2=w2[i], a3=w3[i];
    #pragma unroll
    for (int j=0;j<4;j++){
      float4 x = xl[(4*g+j)*257 + i];
      acc[0][j] += a0.x*x.x + a0.y*x.y + a0.z*x.z + a0.w*x.w;
      acc[1][j] += a1.x*x.x + a1.y*x.y + a1.z*x.z + a1.w*x.w;
      acc[2][j] += a2.x*x.x + a2.y*x.y + a2.z*x.z + a2.w*x.w;
      acc[3][j] += a3.x*x.x + a3.y*x.y + a3.z*x.z + a3.w*x.w;
    }
  }
  return reduce_pick(acc, l);
}

// Producer/consumer flags:
//  arrA[bx]  = i+1 : block bx finished phase A of iter i (Gw/tf visible).
//  arrB[b]   = i+1 : chain block b finished phase B of iter i (h_{i+1} visible).
// All flag stores preceded by __syncthreads() (drains vmcnt for the whole
// block — coherent stores completed at the coherence point). All flag reads
// and cross-block data reads are cache-bypassing -> no fences, no invalidates.
__global__ __launch_bounds__(256) void k_seq(
  const float* __restrict__ Whh, const float* __restrict__ Wf1,
  const float* __restrict__ Pw, const float* __restrict__ Pa,
  const float* __restrict__ cf, const float* __restrict__ E,
  const float* __restrict__ C0, const int* __restrict__ ta,
  const int* __restrict__ nfp,
  float* __restrict__ hall, float* __restrict__ c, float* __restrict__ tf,
  float* __restrict__ Gw, int* __restrict__ aall,
  float* __restrict__ loss, int* __restrict__ arrA, int* __restrict__ arrB)
{
  __shared__ float4 xl[16*257];
  __shared__ float sS[64];
  __shared__ int sIdx;
  int tid = threadIdx.x, bx = blockIdx.x;
  int lane = tid & 63, wave = tid >> 6, l = lane & 15, g = lane >> 4;

  for (int i = 0; i <= 96; i++){
    // ---- wait until h_i is visible (chain blocks of iter i-1 done)
    if (i > 0){
      if (tid < 16){
        while (ld_flag(&arrB[tid]) < i) __builtin_amdgcn_s_sleep(8);
      }
    }
    __syncthreads();

    // ---- Phase A: Gw = Whh@h_i (256 tiles) ; tf = relu(Wf1_h@h_i + cf) (64 tiles)
    {
      const float* hsrc = hall + (size_t)i*16384;
      float2* xl2 = (float2*)xl;
      for (int idx=tid; idx<8192; idx+=256){
        int b2 = idx>>9, kk = idx&511;
        xl2[b2*514 + kk] = ld_cohf2(hsrc + b2*1024 + kk*2);
      }
      __syncthreads();
      {
        float v = tile16(Whh, bx*16 + wave*4, 1024, xl, l, g);
        int row = bx*16 + wave*4 + (l>>2);
        int b = g*4 + (l&3);
        st_cohf(&Gw[b*4096 + row], v);
      }
      if (bx < 64){
        float v = tile16(Wf1, bx*16 + wave*4, 1536, xl, l, g);
        int rw = bx*16 + wave*4 + (l>>2);
        int b = g*4 + (l&3);
        st_cohf(&tf[b*1024 + rw], fmaxf(v + cf[b*1024 + rw], 0.f));
      }
    }
    __syncthreads();                 // drains all vmem stores of this block
    if (tid == 0) st_flag(&arrA[bx], i+1);

    // ---- Phase B: chain blocks only
    if (bx < 16){
      int b = bx;
      while (ld_flag(&arrA[tid]) < i+1) __builtin_amdgcn_s_sleep(8);
      __syncthreads();
      float* tfl = (float*)xl;
      for (int j=tid; j<512; j+=256)
        ((float2*)tfl)[j] = ld_cohf2(tf + b*1024 + j*2);
      __syncthreads();
      int ai = 0;
      if (i >= 1){
        int f = tid>>2, q = tid&3;
        const float4* Er = (const float4*)(E + (size_t)(b*64+f)*1024) + q*64;
        const float4* tf4 = (const float4*)tfl + q*64;
        float s_ = 0.f;
        #pragma unroll 4
        for (int k2=0;k2<64;k2++){
          float4 e = Er[k2], x = tf4[k2];
          s_ += e.x*x.x + e.y*x.y + e.z*x.z + e.w*x.w;
        }
        s_ += __shfl_xor(s_,1); s_ += __shfl_xor(s_,2);
        if (q==0) sS[f] = s_ + C0[b*64+f];
        __syncthreads();
        if (tid < 64){
          int nf = nfp[b];
          float s = sS[tid];
          float mx = s;
          #pragma unroll
          for (int m=32;m>0;m>>=1) mx = fmaxf(mx, __shfl_xor(mx,m));
          float p = expf(s - mx);
          float ps = wsum64(p);
          p /= ps;
          bool mask = (tid < nf) || (tid == 63);
          float mval = mask ? (p + EPSF) : EPSF;
          float msum = wsum64(mval);
          float bv = mval; int bi2 = tid;
          #pragma unroll
          for (int m=32;m>0;m>>=1){
            float ov = __shfl_xor(bv,m); int oi = __shfl_xor(bi2,m);
            if (ov > bv || (ov == bv && oi < bi2)){ bv = ov; bi2 = oi; }
          }
          int at = ta[b*TT + (i-1)];
          float mat = __shfl(mval, at);
          if (tid == 0){
            atomicAdd(loss, -(logf(mat) - logf(msum)));
            sIdx = bi2;
          }
        }
        __syncthreads();
        ai = sIdx;
        if (tid == 0) aall[(i-1)*16 + b] = ai;
      }
      if (i <= 95){
        const float* gb = Gw + b*4096;
        const float* pw = Pw + (size_t)(b*96 + i)*4096;
        const float* pa = Pa + (size_t)(b*64 + ai)*4096;
        bool hasA = (i >= 1);
        for (int j=tid; j<1024; j+=256){
          float ig = ld_cohf(gb+j)      + pw[j]      + (hasA ? pa[j]      : 0.f);
          float fg = ld_cohf(gb+1024+j) + pw[1024+j] + (hasA ? pa[1024+j] : 0.f);
          float gg = ld_cohf(gb+2048+j) + pw[2048+j] + (hasA ? pa[2048+j] : 0.f);
          float og = ld_cohf(gb+3072+j) + pw[3072+j] + (hasA ? pa[3072+j] : 0.f);
          float co = c[b*1024 + j];
          float cn = sigm(fg)*co + sigm(ig)*tanhf(gg);
          c[b*1024 + j] = cn;
          st_cohf(&hall[((size_t)(i+1)*16 + b)*1024 + j], sigm(og)*tanhf(cn));
        }
      }
      __syncthreads();               // drain h stores (all threads of block)
      if (tid == 0) st_flag(&arrB[b], i+1);
    }
  }
}

// ---------------- phase 2: batched over all (b,t) ----------------

__global__ __launch_bounds__(256) void k2_cvp(
  const float* __restrict__ Wc1, const float* __restrict__ Wv1,
  const float* __restrict__ Wp1, const float* __restrict__ hall,
  const float* __restrict__ Ph, const int* __restrict__ aall,
  const float* __restrict__ bc1, const float* __restrict__ bv1,
  const float* __restrict__ bp1, float* __restrict__ tcvp)
{
  __shared__ float4 xl[16*129];
  int tid = threadIdx.x, lane = tid & 63, wave = tid >> 6;
  int l = lane & 15, g = lane >> 4;
  int seg = blockIdx.x >> 6;
  int rl0 = (blockIdx.x & 63)*16 + wave*4;
  const float* W = (seg==0)?Wc1:(seg==1)?Wv1:Wp1;
  const float4* h4 = (const float4*)hall + (size_t)(16 + blockIdx.y*16)*256;
  float acc[4][4] = {};
  for (int kc=0; kc<2; kc++){
    for (int idx=tid; idx<2048; idx+=256){
      int cc = idx>>7, i = idx&127;
      xl[cc*129+i] = h4[cc*256 + kc*128 + i];
    }
    __syncthreads();
    const float4* w0 = (const float4*)(W + (size_t)(rl0+0)*1536) + kc*128;
    const float4* w1 = (const float4*)(W + (size_t)(rl0+1)*1536) + kc*128;
    const float4* w2 = (const float4*)(W + (size_t)(rl0+2)*1536) + kc*128;
    const float4* w3 = (const float4*)(W + (size_t)(rl0+3)*1536) + kc*128;
    core_chunk(w0,w1,w2,w3, xl, l, g, acc);
    __syncthreads();
  }
  float v = reduce_pick(acc, l);
  int rl = rl0 + (l>>2);
  int n = blockIdx.y*16 + g*4 + (l&3);
  int b = n & 15;
  int ai = aall[n];
  const float* bias = (seg==0)?bc1:(seg==1)?bv1:bp1;
  float vv = v + Ph[((size_t)(b*64+ai))*3072 + seg*1024 + rl] + bias[rl];
  tcvp[(size_t)n*3072 + seg*1024 + rl] = fmaxf(vv, 0.f);
}

__global__ __launch_bounds__(256) void k2_heads2(
  const float* __restrict__ Wv2, const float* __restrict__ bv2,
  const float* __restrict__ Wp2, const float* __restrict__ bp2,
  const float* __restrict__ Wc2, const float* __restrict__ bc2,
  const float* __restrict__ tcvp, unsigned short* __restrict__ kvh,
  float* __restrict__ kpall, float* __restrict__ zlall)
{
  __shared__ float4 xl[16*129];
  int tid = threadIdx.x, lane = tid & 63, wave = tid >> 6;
  int l = lane & 15, g = lane >> 4;
  int bx = blockIdx.x;
  int seg = (bx < 32) ? 0 : (bx < 39) ? 1 : 2;
  int rb  = (seg==0) ? bx*16 : (seg==1) ? (bx-32)*16 : 0;
  int rl0 = rb + wave*4;
  const float* WS = (seg==0)?Wv2:(seg==1)?Wp2:Wc2;
  int maxr = (seg==0)?511:(seg==1)?99:0;
  int xoff4 = (seg==0)?256:(seg==1)?512:0;
  const float4* X4 = (const float4*)tcvp;
  float acc[4][4] = {};
  for (int kc=0; kc<2; kc++){
    for (int idx=tid; idx<2048; idx+=256){
      int cc = idx>>7, i = idx&127;
      xl[cc*129+i] = X4[(size_t)(blockIdx.y*16+cc)*768 + xoff4 + kc*128 + i];
    }
    __syncthreads();
    const float4* w0 = (const float4*)(WS + (size_t)min(rl0+0,maxr)*1024) + kc*128;
    const float4* w1 = (const float4*)(WS + (size_t)min(rl0+1,maxr)*1024) + kc*128;
    const float4* w2 = (const float4*)(WS + (size_t)min(rl0+2,maxr)*1024) + kc*128;
    const float4* w3 = (const float4*)(WS + (size_t)min(rl0+3,maxr)*1024) + kc*128;
    core_chunk(w0,w1,w2,w3, xl, l, g, acc);
    __syncthreads();
  }
  float v = reduce_pick(acc, l);
  int rl = rl0 + (l>>2);
  int n = blockIdx.y*16 + g*4 + (l&3);
  if (seg==0) kvh[(size_t)n*512 + rl] = f2bf(v + bv2[rl]);
  else if (seg==1){ if (rl < 100) kpall[n*128 + rl] = v + bp2[rl]; }
  else { if (rl == 0) zlall[n] = v + bc2[0]; }
}

__global__ __launch_bounds__(256) void k2_vocab(
  const unsigned short* __restrict__ embh, const unsigned short* __restrict__ kvh,
  float2* __restrict__ part)
{
  int wid = blockIdx.x*4 + (threadIdx.x>>6);
  int lane = threadIdx.x & 63;
  int mtile = wid % 500, ntile = wid / 500;
  int mrow = mtile*64 + (lane&15);
  int ncol = ntile*64 + (lane&15);
  int ko = (lane>>4)*8;
  f4v acc[4][4];
  #pragma unroll
  for (int i=0;i<4;i++)
  #pragma unroll
  for (int j=0;j<4;j++)
  #pragma unroll
  for (int r=0;r<4;r++) acc[i][j][r] = 0.f;
  for (int kk=0; kk<512; kk+=32){
    short8 af[4], bfr[4];
    #pragma unroll
    for (int i=0;i<4;i++)
      af[i] = *(const short8*)(embh + (size_t)(mrow+16*i)*512 + kk + ko);
    #pragma unroll
    for (int i=0;i<4;i++)
      bfr[i] = *(const short8*)(kvh + (size_t)(ncol+16*i)*512 + kk + ko);
    #pragma unroll
    for (int i=0;i<4;i++)
      #pragma unroll
      for (int j=0;j<4;j++)
        acc[i][j] = __builtin_amdgcn_mfma_f32_16x16x32_bf16(af[i], bfr[j], acc[i][j], 0,0,0);
  }
  int q = lane>>4;
  #pragma unroll
  for (int j=0;j<4;j++){
    float mx = -3.4e38f;
    #pragma unroll
    for (int i=0;i<4;i++)
    #pragma unroll
    for (int r=0;r<4;r++) mx = fmaxf(mx, acc[i][j][r]);
    mx = fmaxf(mx, __shfl_xor(mx,16));
    mx = fmaxf(mx, __shfl_xor(mx,32));
    float s = 0.f;
    #pragma unroll
    for (int i=0;i<4;i++)
    #pragma unroll
    for (int r=0;r<4;r++) s += expf(acc[i][j][r] - mx);
    s += __shfl_xor(s,16);
    s += __shfl_xor(s,32);
    if (q==0){
      int col = ntile*64 + 16*j + (lane&15);
      part[(size_t)col*500 + mtile] = make_float2(mx, s);
    }
  }
}

__global__ __launch_bounds__(256) void k2_vfin(
  const float2* __restrict__ part, const unsigned short* __restrict__ embh,
  const unsigned short* __restrict__ kvh, const int* __restrict__ tw,
  const int* __restrict__ tz, float* __restrict__ loss)
{
  __shared__ float red[4];
  int n = blockIdx.x, tid = threadIdx.x;
  int t = n>>4, b = n&15;
  float mx = -3.4e38f;
  for (int i=tid; i<500; i+=256) mx = fmaxf(mx, part[(size_t)n*500+i].x);
  #pragma unroll
  for (int m=32;m>0;m>>=1) mx = fmaxf(mx, __shfl_xor(mx,m));
  if ((tid&63)==0) red[tid>>6] = mx;
  __syncthreads();
  float M = fmaxf(fmaxf(red[0],red[1]), fmaxf(red[2],red[3]));
  __syncthreads();
  float s = 0.f;
  for (int i=tid; i<500; i+=256){
    float2 p = part[(size_t)n*500+i];
    s += p.y * expf(p.x - M);
  }
  s = wsum64(s);
  if ((tid&63)==0) red[tid>>6] = s;
  __syncthreads();
  float S = red[0]+red[1]+red[2]+red[3];
  __syncthreads();
  int w = tw[b*96+t];
  float d = 0.f;
  {
    const unsigned short* er = embh + (size_t)w*512;
    const unsigned short* kr = kvh + (size_t)n*512;
    for (int i=tid; i<512; i+=256) d += bf2f(er[i])*bf2f(kr[i]);
  }
  d = wsum64(d);
  if ((tid&63)==0) red[tid>>6] = d;
  __syncthreads();
  if (tid==0 && tz[b*96+t]==0){
    float D = red[0]+red[1]+red[2]+red[3];
    atomicAdd(loss, -(D - (M + logf(S))));
  }
}

__global__ __launch_bounds__(128) void k2_posz(
  const float* __restrict__ kpall, const float* __restrict__ zlall,
  const float* __restrict__ WP, const float* __restrict__ bP,
  const float* __restrict__ pmask, const int* __restrict__ tw,
  const int* __restrict__ ta, const int* __restrict__ tz,
  float* __restrict__ loss)
{
  __shared__ float pp[100];
  int n = blockIdx.x, tid = threadIdx.x;
  int t = n>>4, b = n&15;
  if (tid < 100){
    float s = bP[tid];
    const float* wr = WP + tid*100;
    const float* kp = kpall + n*128;
    for (int j=0;j<100;j++) s += wr[j]*kp[j];
    pp[tid] = s;
  }
  __syncthreads();
  if (tid == 0){
    float u = zlall[n];
    int z = tz[b*96+t], w = tw[b*96+t], at = ta[b*96+t];
    float tot = z ? softplus(-u) : softplus(u);
    if (z){
      float mxv = -1e30f;
      for (int l2=0;l2<100;l2++) mxv = fmaxf(mxv, pp[l2]);
      float se = 0.f;
      for (int l2=0;l2<100;l2++) se += expf(pp[l2]-mxv);
      const float* pm = pmask + ((size_t)b*64 + at)*100;
      float msum = 0.f, mw = 0.f;
      for (int l2=0;l2<100;l2++){
        float m = pm[l2]*(expf(pp[l2]-mxv)/se) + EPSF;
        msum += m;
        if (l2==w) mw = m;
      }
      tot += -(logf(mw) - logf(msum));
    }
    atomicAdd(loss, tot);
  }
}

// ---------------- phase 0: once-per-launch precompute ----------------

__global__ void k_cvt_emb(const float* __restrict__ emb, unsigned* __restrict__ out){
  const int n = VV*512/2;
  for (int idx = blockIdx.x*256 + threadIdx.x; idx < n; idx += gridDim.x*256){
    float2 v = ((const float2*)emb)[idx];
    unsigned a = __float_as_uint(v.x), b = __float_as_uint(v.y);
    unsigned ra = (a + 0x7fffu + ((a>>16)&1u)) >> 16;
    unsigned rb = (b + 0x7fffu + ((b>>16)&1u)) >> 16;
    out[idx] = ra | (rb<<16);
  }
}

__global__ void k_setup(const float* __restrict__ fe, const int* __restrict__ nfp,
                        float* __restrict__ e_k){
  int b = blockIdx.x, tid = threadIdx.x;
  int nf = nfp[b];
  for (int d=tid; d<512; d+=256){
    float s = 0.f;
    for (int f=0; f<nf; f++) s += fe[((size_t)b*64+f)*512 + d];
    e_k[b*512+d] = s/(float)nf;
  }
}

__global__ __launch_bounds__(256) void k_pre_pa(
  const float* __restrict__ Wih, const float* __restrict__ fe, float* __restrict__ Pa)
{
  __shared__ float4 xl[16*129];
  int tid = threadIdx.x, lane = tid & 63, wave = tid >> 6;
  int l = lane & 15, g = lane >> 4;
  int row0 = blockIdx.x*16 + wave*4;
  int c0 = blockIdx.y*16;
  const float4* fe4 = (const float4*)fe;
  for (int idx=tid; idx<2048; idx+=256){
    int cc = idx>>7, i = idx&127;
    xl[cc*129+i] = fe4[(size_t)(c0+cc)*128 + i];
  }
  __syncthreads();
  const float4* w0 = (const float4*)(Wih + (size_t)(row0+0)*1124);
  const float4* w1 = (const float4*)(Wih + (size_t)(row0+1)*1124);
  const float4* w2 = (const float4*)(Wih + (size_t)(row0+2)*1124);
  const float4* w3 = (const float4*)(Wih + (size_t)(row0+3)*1124);
  float acc[4][4] = {};
  core_chunk(w0,w1,w2,w3, xl, l, g, acc);
  float v = reduce_pick(acc, l);
  int row = row0 + (l>>2), c = c0 + g*4 + (l&3);
  Pa[(size_t)c*4096 + row] = v;
}

__global__ __launch_bounds__(256) void k_pre_ph(
  const float* __restrict__ Wc1, const float* __restrict__ Wv1,
  const float* __restrict__ Wp1, const float* __restrict__ fe, float* __restrict__ Ph)
{
  __shared__ float4 xl[16*129];
  int tid = threadIdx.x, lane = tid & 63, wave = tid >> 6;
  int l = lane & 15, g = lane >> 4;
  int row0 = blockIdx.x*16 + wave*4;
  int head = row0 >> 10, rl0 = row0 & 1023;
  const float* W = (head==0)?Wc1:(head==1)?Wv1:Wp1;
  int c0 = blockIdx.y*16;
  const float4* fe4 = (const float4*)fe;
  for (int idx=tid; idx<2048; idx+=256){
    int cc = idx>>7, i = idx&127;
    xl[cc*129+i] = fe4[(size_t)(c0+cc)*128 + i];
  }
  __syncthreads();
  const float4* w0 = (const float4*)(W + (size_t)(rl0+0)*1536 + 1024);
  const float4* w1 = (const float4*)(W + (size_t)(rl0+1)*1536 + 1024);
  const float4* w2 = (const float4*)(W + (size_t)(rl0+2)*1536 + 1024);
  const float4* w3 = (const float4*)(W + (size_t)(rl0+3)*1536 + 1024);
  float acc[4][4] = {};
  core_chunk(w0,w1,w2,w3, xl, l, g, acc);
  float v = reduce_pick(acc, l);
  int row = row0 + (l>>2), c = c0 + g*4 + (l&3);
  Ph[(size_t)c*3072 + row] = v;
}

__global__ __launch_bounds__(256) void k_pre_pw(
  const float* __restrict__ Wih, const float* __restrict__ emb,
  const int* __restrict__ tw, const int* __restrict__ tz,
  const float* __restrict__ bih, const float* __restrict__ bhh,
  float* __restrict__ Pw)
{
  __shared__ float4 xl[16*129];
  int tid = threadIdx.x, lane = tid & 63, wave = tid >> 6;
  int l = lane & 15, g = lane >> 4;
  int row0 = blockIdx.x*16 + wave*4;
  int c0 = blockIdx.y*16;
  for (int idx=tid; idx<2048; idx+=256){
    int cc = idx>>7, i = idx&127;
    int c = c0+cc, b = c/96, t2 = c - b*96;
    int w=0, z=0;
    if (t2>0){ w = tw[b*96+t2-1]; z = tz[b*96+t2-1]; }
    float4 v = make_float4(0.f,0.f,0.f,0.f);
    if (z==0) v = ((const float4*)emb)[(size_t)w*128 + i];
    xl[cc*129+i] = v;
  }
  __syncthreads();
  const float4* w0 = (const float4*)(Wih + (size_t)(row0+0)*1124 + 512);
  const float4* w1 = (const float4*)(Wih + (size_t)(row0+1)*1124 + 512);
  const float4* w2 = (const float4*)(Wih + (size_t)(row0+2)*1124 + 512);
  const float4* w3 = (const float4*)(Wih + (size_t)(row0+3)*1124 + 512);
  float acc[4][4] = {};
  core_chunk(w0,w1,w2,w3, xl, l, g, acc);
  float v = reduce_pick(acc, l);
  int row = row0 + (l>>2), c = c0 + g*4 + (l&3);
  int b = c/96, t2 = c - b*96;
  int w=0, z=0;
  if (t2>0){ w = tw[b*96+t2-1]; z = tz[b*96+t2-1]; }
  v += bih[row] + bhh[row];
  if (z) v += Wih[(size_t)row*1124 + 1024 + w];
  Pw[(size_t)c*4096 + row] = v;
}

__global__ __launch_bounds__(256) void k_pre_cf(
  const float* __restrict__ Wf1, const float* __restrict__ bf1,
  const float* __restrict__ e_k, float* __restrict__ cf)
{
  __shared__ float4 xl[16*129];
  int tid = threadIdx.x, lane = tid & 63, wave = tid >> 6;
  int l = lane & 15, g = lane >> 4;
  int row0 = blockIdx.x*16 + wave*4;
  const float4* ek4 = (const float4*)e_k;
  for (int idx=tid; idx<2048; idx+=256){
    int cc = idx>>7, i = idx&127;
    xl[cc*129+i] = ek4[cc*128 + i];
  }
  __syncthreads();
  const float4* w0 = (const float4*)(Wf1 + (size_t)(row0+0)*1536 + 1024);
  const float4* w1 = (const float4*)(Wf1 + (size_t)(row0+1)*1536 + 1024);
  const float4* w2 = (const float4*)(Wf1 + (size_t)(row0+2)*1536 + 1024);
  const float4* w3 = (const float4*)(Wf1 + (size_t)(row0+3)*1536 + 1024);
  float acc[4][4] = {};
  core_chunk(w0,w1,w2,w3, xl, l, g, acc);
  float v = reduce_pick(acc, l);
  int row = row0 + (l>>2), b = g*4 + (l&3);
  cf[b*1024 + row] = v + bf1[row];
}

// E[c][j] = sum_d fe[c][d] * Wf2[d][j]   (c = b*64+f)
__global__ __launch_bounds__(256) void k_pre_e(
  const float* __restrict__ fe, const float* __restrict__ Wf2, float* __restrict__ E)
{
  __shared__ float fel[16*512];
  int tid = threadIdx.x;
  int c0 = blockIdx.x*16;
  int j0 = blockIdx.y*256;
  const float4* fe4 = (const float4*)fe;
  for (int idx=tid; idx<2048; idx+=256)
    ((float4*)fel)[idx] = fe4[(size_t)c0*128 + idx];
  __syncthreads();
  int j = j0 + tid;
  float acc[16] = {};
  for (int d=0; d<512; d++){
    float wv = Wf2[d*1024 + j];
    #pragma unroll
    for (int cc=0; cc<16; cc++) acc[cc] += fel[cc*512+d]*wv;
  }
  #pragma unroll
  for (int cc=0; cc<16; cc++) E[(size_t)(c0+cc)*1024 + j] = acc[cc];
}

// C0[c] = fe[c] . bf2
__global__ void k_pre_c0(const float* __restrict__ fe, const float* __restrict__ bf2,
                         float* __restrict__ C0)
{
  int b = blockIdx.x, tid = threadIdx.x;
  int f = tid>>2, q = tid&3;
  const float4* fr = (const float4*)(fe + (size_t)(b*64+f)*512) + q*32;
  const float4* b4 = (const float4*)bf2 + q*32;
  float s = 0.f;
  for (int k=0;k<32;k++){ float4 a=fr[k], w=b4[k]; s += a.x*w.x+a.y*w.y+a.z*w.z+a.w*w.w; }
  s += __shfl_xor(s,1); s += __shfl_xor(s,2);
  if (q==0) C0[b*64+f] = s;
}

__global__ void k_out(const float* __restrict__ loss, float* __restrict__ out){
  out[0] = loss[0];
}

extern "C" void kernel_launch(void* const* d_in, const int* in_sizes, int n_in,
                              void* d_out, int out_size, void* d_ws, size_t ws_size,
                              hipStream_t stream)
{
  const float* fe   = (const float*)d_in[0];
  const float* pmask= (const float*)d_in[1];
  const float* emb  = (const float*)d_in[2];
  const float* Wih  = (const float*)d_in[3];
  const float* Whh  = (const float*)d_in[4];
  const float* bih  = (const float*)d_in[5];
  const float* bhh  = (const float*)d_in[6];
  const float* Wf1  = (const float*)d_in[7];
  const float* bf1  = (const float*)d_in[8];
  const float* Wf2  = (const float*)d_in[9];
  const float* bf2  = (const float*)d_in[10];
  const float* Wc1  = (const float*)d_in[11];
  const float* bc1  = (const float*)d_in[12];
  const float* Wc2  = (const float*)d_in[13];
  const float* bc2  = (const float*)d_in[14];
  const float* Wv1  = (const float*)d_in[15];
  const float* bv1  = (const float*)d_in[16];
  const float* Wv2  = (const float*)d_in[17];
  const float* bv2  = (const float*)d_in[18];
  const float* Wp1  = (const float*)d_in[19];
  const float* bp1  = (const float*)d_in[20];
  const float* Wp2  = (const float*)d_in[21];
  const float* bp2  = (const float*)d_in[22];
  const float* WP   = (const float*)d_in[23];
  const float* bP   = (const float*)d_in[24];
  const int* tw  = (const int*)d_in[25];
  const int* ta  = (const int*)d_in[26];
  const int* tz  = (const int*)d_in[27];
  const int* nfp = (const int*)d_in[28];

  float* w = (float*)d_ws;
  float*    loss  = w + 0;                        // 8 floats
  int*      arrA  = (int*)(w + 8);                // 256
  int*      arrB  = (int*)(w + 264);              // 16 (pad to 512)
  float*    c     = w + 512;                      // 16384
  float*    hall  = w + 16896;                    // 97*16384 (slot0 zeroed)
  int*      aall  = (int*)(w + 1606144);          // 1536
  float*    tf    = w + 1607680;                  // 16384
  float*    Gw    = w + 1624064;                  // 65536
  float*    e_k   = w + 1689600;                  // 8192
  float*    cf    = w + 1697792;                  // 16384
  float*    E     = w + 1714176;                  // 1048576
  float*    C0    = w + 2762752;                  // 1024
  float*    kpall = w + 2763776;                  // 196608
  float*    zlall = w + 2960384;                  // 1536
  float*    tcvp  = w + 2961920;                  // 4718592
  float2*   part  = (float2*)(w + 7680512);       // 1536000 floats
  unsigned short* kvh = (unsigned short*)(w + 9216512);  // 786432 ushorts
  float*    Pa    = w + 9609728;                  // 4194304
  float*    Ph    = w + 13804032;                 // 3145728
  float*    Pw    = w + 16949760;                 // 6291456
  unsigned* embbf = (unsigned*)(w + 23241216);    // 8192000 uints
  const unsigned short* embh = (const unsigned short*)embbf;

  // zero loss, flags, c, hall slot 0
  hipMemsetAsync(d_ws, 0, (size_t)(512 + 16384 + 16384)*4, stream);
  k_cvt_emb<<<8192,256,0,stream>>>(emb, embbf);
  k_setup<<<16,256,0,stream>>>(fe, nfp, e_k);
  k_pre_pa<<<dim3(256,64),256,0,stream>>>(Wih, fe, Pa);
  k_pre_ph<<<dim3(192,64),256,0,stream>>>(Wc1, Wv1, Wp1, fe, Ph);
  k_pre_pw<<<dim3(256,96),256,0,stream>>>(Wih, emb, tw, tz, bih, bhh, Pw);
  k_pre_cf<<<64,256,0,stream>>>(Wf1, bf1, e_k, cf);
  k_pre_e<<<dim3(64,4),256,0,stream>>>(fe, Wf2, E);
  k_pre_c0<<<16,256,0,stream>>>(fe, bf2, C0);

  k_seq<<<256,256,0,stream>>>(Whh, Wf1, Pw, Pa, cf, E, C0, ta, nfp,
                              hall, c, tf, Gw, aall, loss, arrA, arrB);

  k2_cvp<<<dim3(192,96),256,0,stream>>>(Wc1, Wv1, Wp1, hall, Ph, aall,
                                        bc1, bv1, bp1, tcvp);
  k2_heads2<<<dim3(40,96),256,0,stream>>>(Wv2, bv2, Wp2, bp2, Wc2, bc2,
                                          tcvp, kvh, kpall, zlall);
  k2_vocab<<<3000,256,0,stream>>>(embh, kvh, part);
  k2_vfin<<<1536,256,0,stream>>>(part, embh, kvh, tw, tz, loss);
  k2_posz<<<1536,128,0,stream>>>(kpall, zlall, WP, bP, pmask, tw, ta, tz, loss);
  k_out<<<1,1,0,stream>>>(loss, (float*)d_out);
}